// Round 1
// baseline (642.929 us; speedup 1.0000x reference)
//
#include <hip/hip_runtime.h>
#include <hip/hip_bf16.h>

#define NN 50000
#define INF 256
#define NH 8
#define OUTF 64
#define NC 512   // NH*OUTF

typedef __attribute__((ext_vector_type(8))) short bf16x8;
typedef __attribute__((ext_vector_type(4))) float f32x4;

__device__ __forceinline__ unsigned short f2bf(float f){
  unsigned u = __float_as_uint(f);
  u += 0x7FFFu + ((u>>16)&1u);
  return (unsigned short)(u>>16);
}

// ---------------- GEMM: t[n][h*64+o] = sum_f x[n][f]*W[h*64+o][f], bf16 out
__global__ __launch_bounds__(256) void k_gemm(const float* __restrict__ x,
                                              const float* __restrict__ W,
                                              unsigned short* __restrict__ tb){
  __shared__ unsigned short As[64*256];
  __shared__ unsigned short Bs[64*256];
  const int tid = threadIdx.x;
  const int brow = blockIdx.x, bcol = blockIdx.y;

  // stage x tile (64 rows x 256 K) f32 -> bf16, XOR-swizzled chunks of 16B
  {
    int r  = tid>>2;
    int cb = (tid&3)*64;
    long gr = (long)brow*64 + r;
    bool valid = gr < NN;
    const float* xr = x + gr*INF;
    for (int i=0;i<16;i++){
      int c = cb + i*4;
      float4 v = valid ? *(const float4*)(xr + c) : make_float4(0.f,0.f,0.f,0.f);
      ushort4 b; b.x=f2bf(v.x); b.y=f2bf(v.y); b.z=f2bf(v.z); b.w=f2bf(v.w);
      int addr = r*512 + ((((c>>3) ^ (r&7)))<<4) + ((c&7)<<1);
      *(ushort4*)((char*)As + addr) = b;
    }
    int wr = bcol*64 + r;          // 0..511, always valid
    const float* Wr = W + wr*INF;
    for (int i=0;i<16;i++){
      int c = cb + i*4;
      float4 v = *(const float4*)(Wr + c);
      ushort4 b; b.x=f2bf(v.x); b.y=f2bf(v.y); b.z=f2bf(v.z); b.w=f2bf(v.w);
      int addr = r*512 + ((((c>>3) ^ (r&7)))<<4) + ((c&7)<<1);
      *(ushort4*)((char*)Bs + addr) = b;
    }
  }
  __syncthreads();

  const int w = tid>>6, l = tid&63;
  const int col = w*16 + (l&15);       // within-tile output col
  f32x4 acc[4] = {};
  for (int ks=0; ks<8; ks++){
    int chunkB = (ks*4 + (l>>4)) ^ (col&7);
    bf16x8 bfrag = *(const bf16x8*)((char*)Bs + col*512 + (chunkB<<4));
#pragma unroll
    for (int mt=0; mt<4; mt++){
      int ar = mt*16 + (l&15);
      int chunkA = (ks*4 + (l>>4)) ^ (ar&7);
      bf16x8 afrag = *(const bf16x8*)((char*)As + ar*512 + (chunkA<<4));
      acc[mt] = __builtin_amdgcn_mfma_f32_16x16x32_bf16(afrag, bfrag, acc[mt], 0,0,0);
    }
  }
  const int gc = bcol*64 + col;
#pragma unroll
  for (int mt=0; mt<4; mt++){
#pragma unroll
    for (int j=0;j<4;j++){
      long gr = (long)brow*64 + mt*16 + (l>>4)*4 + j;
      if (gr < NN) tb[gr*NC + gc] = f2bf(acc[mt][j]);
    }
  }
}

// ---------------- Al/Ar: per (node, head) dots of t row with attention vecs
__global__ __launch_bounds__(256) void k_alar(const unsigned short* __restrict__ tb,
                                              const float* __restrict__ Av,
                                              float* __restrict__ Al, float* __restrict__ Ar){
  const int tid = threadIdx.x, l = tid&63;
  const long n = (long)blockIdx.x*4 + (tid>>6);
  if (n >= NN) return;
  const int h = l>>3;
  uint4 pv = *(const uint4*)(tb + n*NC + l*8);
  float f[8];
  f[0]=__uint_as_float(pv.x<<16); f[1]=__uint_as_float(pv.x&0xffff0000u);
  f[2]=__uint_as_float(pv.y<<16); f[3]=__uint_as_float(pv.y&0xffff0000u);
  f[4]=__uint_as_float(pv.z<<16); f[5]=__uint_as_float(pv.z&0xffff0000u);
  f[6]=__uint_as_float(pv.w<<16); f[7]=__uint_as_float(pv.w&0xffff0000u);
  const float* ap = Av + h*128 + (l&7)*8;
  float sl=0.f, sr=0.f;
#pragma unroll
  for (int j=0;j<8;j++){ sl += f[j]*ap[j]; sr += f[j]*ap[j+64]; }
  sl += __shfl_xor(sl,1,64); sl += __shfl_xor(sl,2,64); sl += __shfl_xor(sl,4,64);
  sr += __shfl_xor(sr,1,64); sr += __shfl_xor(sr,2,64); sr += __shfl_xor(sr,4,64);
  if ((l&7)==0){ Al[n*NH+h]=sl; Ar[n*NH+h]=sr; }
}

// ---------------- CSR build
__global__ void k_hist(const int* __restrict__ src, int* __restrict__ cnt, int E){
  int e = blockIdx.x*256 + threadIdx.x;
  if (e < E) atomicAdd(&cnt[src[e]], 1);
}

__global__ __launch_bounds__(256) void k_scan1(const int* __restrict__ in, int* __restrict__ out,
                                               int* __restrict__ bsums, int n){
  __shared__ int lds[256];
  const int tid = threadIdx.x;
  const int base = blockIdx.x*1024 + tid*4;
  int v0=0,v1=0,v2=0,v3=0;
  if (base+3 < n){ int4 t = *(const int4*)(in+base); v0=t.x;v1=t.y;v2=t.z;v3=t.w; }
  else {
    if (base   < n) v0 = in[base];
    if (base+1 < n) v1 = in[base+1];
    if (base+2 < n) v2 = in[base+2];
    if (base+3 < n) v3 = in[base+3];
  }
  int s = v0+v1+v2+v3;
  lds[tid] = s; __syncthreads();
  for (int off=1; off<256; off<<=1){
    int add = (tid>=off)? lds[tid-off] : 0;
    __syncthreads();
    lds[tid] += add;
    __syncthreads();
  }
  int excl = lds[tid] - s;
  if (base   < n) out[base]   = excl;
  if (base+1 < n) out[base+1] = excl+v0;
  if (base+2 < n) out[base+2] = excl+v0+v1;
  if (base+3 < n) out[base+3] = excl+v0+v1+v2;
  if (tid==255) bsums[blockIdx.x] = lds[255];
}

__global__ void k_scan2(int* __restrict__ bs, int nb){
  int tid = threadIdx.x;
  int v = (tid<nb)? bs[tid] : 0;
  int orig = v;
  for (int off=1; off<64; off<<=1){
    int y = __shfl_up(v, off, 64);
    if (tid>=off) v += y;
  }
  if (tid<nb) bs[tid] = v - orig;   // exclusive block offsets
}

__global__ __launch_bounds__(256) void k_scan3(int* __restrict__ rp, int* __restrict__ cursor,
                                               const int* __restrict__ bs, int n){
  const int tid = threadIdx.x;
  const int base = blockIdx.x*1024 + tid*4;
  const int o = bs[blockIdx.x];
#pragma unroll
  for (int j=0;j<4;j++){
    int idx = base+j;
    if (idx < n){ int v = rp[idx]+o; rp[idx]=v; cursor[idx]=v; }
  }
}

__global__ void k_scatter(const int* __restrict__ src, const int* __restrict__ dst,
                          int* __restrict__ cursor, int* __restrict__ col, int E){
  int e = blockIdx.x*256 + threadIdx.x;
  if (e < E){
    int s = src[e];
    int p = atomicAdd(&cursor[s], 1);
    col[p] = dst[e];
  }
}

// ---------------- fused softmax-denominator + weighted gather + elu
__global__ __launch_bounds__(256) void k_aggr(const int* __restrict__ row_ptr,
                                              const int* __restrict__ col,
                                              const unsigned short* __restrict__ tb,
                                              const float* __restrict__ Al,
                                              const float* __restrict__ Ar,
                                              float* __restrict__ out){
  const int tid = threadIdx.x, l = tid&63;
  const long n = (long)blockIdx.x*4 + (tid>>6);
  if (n >= NN) return;
  const int h = l>>3;
  const int beg = row_ptr[n], end = row_ptr[n+1];
  const float al = Al[n*NH+h];
  float a0=0,a1=0,a2=0,a3=0,a4=0,a5=0,a6=0,a7=0, den=0;
  for (int i=beg;i<end;i++){
    int d = col[i];
    float w = __expf(al + Ar[(long)d*NH + h]);
    uint4 pv = *(const uint4*)(tb + (long)d*NC + l*8);
    den += w;
    a0 += w*__uint_as_float(pv.x<<16); a1 += w*__uint_as_float(pv.x&0xffff0000u);
    a2 += w*__uint_as_float(pv.y<<16); a3 += w*__uint_as_float(pv.y&0xffff0000u);
    a4 += w*__uint_as_float(pv.z<<16); a5 += w*__uint_as_float(pv.z&0xffff0000u);
    a6 += w*__uint_as_float(pv.w<<16); a7 += w*__uint_as_float(pv.w&0xffff0000u);
  }
  float inv = den>0.f ? 1.f/den : 0.f;
  float4 o0, o1;
  float v;
  v=a0*inv; o0.x = v>0.f? v : expm1f(v);
  v=a1*inv; o0.y = v>0.f? v : expm1f(v);
  v=a2*inv; o0.z = v>0.f? v : expm1f(v);
  v=a3*inv; o0.w = v>0.f? v : expm1f(v);
  v=a4*inv; o1.x = v>0.f? v : expm1f(v);
  v=a5*inv; o1.y = v>0.f? v : expm1f(v);
  v=a6*inv; o1.z = v>0.f? v : expm1f(v);
  v=a7*inv; o1.w = v>0.f? v : expm1f(v);
  float* orow = out + n*NC + l*8;
  *(float4*)orow     = o0;
  *(float4*)(orow+4) = o1;
}

extern "C" void kernel_launch(void* const* d_in, const int* in_sizes, int n_in,
                              void* d_out, int out_size, void* d_ws, size_t ws_size,
                              hipStream_t stream){
  const float* x   = (const float*)d_in[0];
  const int*   src = (const int*)d_in[1];
  const int*   dst = (const int*)d_in[2];
  const float* Ws  = (const float*)d_in[3];
  const float* Av  = (const float*)d_in[4];
  const int E = in_sizes[1];

  char* ws = (char*)d_ws;
  size_t off = 0;
  auto alloc = [&](size_t bytes)->void*{
    void* p = ws + off; off += (bytes + 255) & ~(size_t)255; return p;
  };
  unsigned short* tb   = (unsigned short*)alloc((size_t)NN*NC*2);
  float* Al            = (float*)alloc((size_t)NN*NH*4);
  float* Ar            = (float*)alloc((size_t)NN*NH*4);
  int*   cnt           = (int*)alloc(50304*4);
  int*   row_ptr       = (int*)alloc(50304*4);
  int*   cursor        = (int*)alloc(50304*4);
  int*   bsums         = (int*)alloc(64*4);
  int*   col           = (int*)alloc((size_t)E*4);

  hipMemsetAsync(cnt, 0, 50304*4, stream);

  k_gemm<<<dim3(782,8),256,0,stream>>>(x, Ws, tb);
  k_alar<<<12500,256,0,stream>>>(tb, Av, Al, Ar);
  k_hist<<<(E+255)/256,256,0,stream>>>(src, cnt, E);
  k_scan1<<<49,256,0,stream>>>(cnt, row_ptr, bsums, NN+1);
  k_scan2<<<1,64,0,stream>>>(bsums, 49);
  k_scan3<<<49,256,0,stream>>>(row_ptr, cursor, bsums, NN+1);
  k_scatter<<<(E+255)/256,256,0,stream>>>(src, dst, cursor, col, E);
  k_aggr<<<12500,256,0,stream>>>(row_ptr, col, tb, Al, Ar, (float*)d_out);
}

// Round 2
// 623.807 us; speedup vs baseline: 1.0307x; 1.0307x over previous
//
#include <hip/hip_runtime.h>
#include <hip/hip_bf16.h>

#define NN 50000
#define INF 256
#define NH 8
#define OUTF 64
#define NC 512   // NH*OUTF
#define NROWS 50048  // 782*64, padded rows in tb

typedef __attribute__((ext_vector_type(8))) short bf16x8;
typedef __attribute__((ext_vector_type(4))) float f32x4;

__device__ __forceinline__ unsigned short f2bf(float f){
  unsigned u = __float_as_uint(f);
  u += 0x7FFFu + ((u>>16)&1u);
  return (unsigned short)(u>>16);
}

#define GLOAD_LDS16(g, s) \
  __builtin_amdgcn_global_load_lds((const __attribute__((address_space(1))) void*)(g), \
                                   (__attribute__((address_space(3))) void*)(s), 16, 0, 0)

// ---------- preconvert x -> bf16 tiles (64 rows x 256 K), XOR-swizzled image
__global__ __launch_bounds__(256) void k_prep_x(const float* __restrict__ x,
                                                unsigned short* __restrict__ xs){
  const int tid = threadIdx.x;
  const int r = tid>>2, cb = (tid&3)*64;
  const long gr = (long)blockIdx.x*64 + r;
  char* tile = (char*)(xs + (size_t)blockIdx.x*16384);
  const bool valid = gr < NN;
  const float* xr = x + gr*INF;
#pragma unroll
  for (int i=0;i<16;i++){
    int c = cb + i*4;
    float4 v = valid ? *(const float4*)(xr + c) : make_float4(0.f,0.f,0.f,0.f);
    ushort4 b; b.x=f2bf(v.x); b.y=f2bf(v.y); b.z=f2bf(v.z); b.w=f2bf(v.w);
    int addr = r*512 + ((((c>>3) ^ (r&7)))<<4) + ((c&7)<<1);
    *(ushort4*)(tile + addr) = b;
  }
}

// ---------- preconvert W -> bf16 tiles per head, same swizzled image
__global__ __launch_bounds__(256) void k_prep_w(const float* __restrict__ W,
                                                unsigned short* __restrict__ Wt){
  const int tid = threadIdx.x;
  const int r = tid>>2, cb = (tid&3)*64;
  char* tile = (char*)(Wt + (size_t)blockIdx.x*16384);
  const float* Wr = W + ((long)blockIdx.x*64 + r)*INF;
#pragma unroll
  for (int i=0;i<16;i++){
    int c = cb + i*4;
    float4 v = *(const float4*)(Wr + c);
    ushort4 b; b.x=f2bf(v.x); b.y=f2bf(v.y); b.z=f2bf(v.z); b.w=f2bf(v.w);
    int addr = r*512 + ((((c>>3) ^ (r&7)))<<4) + ((c&7)<<1);
    *(ushort4*)(tile + addr) = b;
  }
}

// ---------- GEMM: stage A once, loop 8 head-tiles of W; fused eAr epilogue
__global__ __launch_bounds__(256) void k_gemm(const unsigned short* __restrict__ xs,
                                              const unsigned short* __restrict__ Wt,
                                              const float* __restrict__ Av,
                                              unsigned short* __restrict__ tb,
                                              float* __restrict__ eAr){
  __shared__ unsigned short As[16384];
  __shared__ unsigned short Bs[16384];
  __shared__ float arp[64];
  const int tid = threadIdx.x, w = tid>>6, l = tid&63;
  const int brow = blockIdx.x;

  // stage A tile (32KB) once
  {
    const char* src = (const char*)xs + (size_t)brow*32768 + w*8192 + l*16;
    char* dst = (char*)As + w*8192;
#pragma unroll
    for (int k=0;k<8;k++) GLOAD_LDS16(src + k*1024, dst + k*1024);
  }
  // stage B tile for head 0
  {
    const char* src = (const char*)Wt + w*8192 + l*16;
    char* dst = (char*)Bs + w*8192;
#pragma unroll
    for (int k=0;k<8;k++) GLOAD_LDS16(src + k*1024, dst + k*1024);
  }
  if (tid < 64) arp[tid] = 0.f;
  asm volatile("s_waitcnt vmcnt(0)");
  __syncthreads();

  const int col = w*16 + (l&15);
  for (int bcol=0; bcol<8; ++bcol){
    f32x4 acc[4] = {};
#pragma unroll
    for (int ks=0; ks<8; ks++){
      int chunkB = (ks*4 + (l>>4)) ^ (col&7);
      bf16x8 bfrag = *(const bf16x8*)((char*)Bs + col*512 + (chunkB<<4));
#pragma unroll
      for (int mt=0; mt<4; mt++){
        int ar_ = mt*16 + (l&15);
        int chunkA = (ks*4 + (l>>4)) ^ (ar_&7);
        bf16x8 afrag = *(const bf16x8*)((char*)As + ar_*512 + (chunkA<<4));
        acc[mt] = __builtin_amdgcn_mfma_f32_16x16x32_bf16(afrag, bfrag, acc[mt], 0,0,0);
      }
    }
    // epilogue: tb write + partial a_r dot
    const float arv = Av[bcol*128 + 64 + col];
    const int gcol = bcol*64 + col;
#pragma unroll
    for (int mt=0; mt<4; mt++){
#pragma unroll
      for (int j=0;j<4;j++){
        int r = mt*16 + (l>>4)*4 + j;
        long gr = (long)brow*64 + r;
        tb[gr*NC + gcol] = f2bf(acc[mt][j]);
        float sv = acc[mt][j] * arv;
        sv += __shfl_xor(sv,1,64); sv += __shfl_xor(sv,2,64);
        sv += __shfl_xor(sv,4,64); sv += __shfl_xor(sv,8,64);
        if ((l&15)==0) atomicAdd(&arp[r], sv);
      }
    }
    __syncthreads();
    if (bcol < 7){
      const char* src = (const char*)Wt + (size_t)(bcol+1)*32768 + w*8192 + l*16;
      char* dst = (char*)Bs + w*8192;
#pragma unroll
      for (int k=0;k<8;k++) GLOAD_LDS16(src + k*1024, dst + k*1024);
    }
    if (tid < 64){
      long gr = (long)brow*64 + tid;
      eAr[gr*NH + bcol] = (gr < NN) ? __expf(arp[tid]) : 0.f;
      arp[tid] = 0.f;
    }
    asm volatile("s_waitcnt vmcnt(0)");
    __syncthreads();
  }
}

// ---------------- CSR build (counts padded to multiples of 4)
__global__ void k_hist(const int* __restrict__ src, int* __restrict__ cnt, int E){
  int e = blockIdx.x*256 + threadIdx.x;
  if (e < E) atomicAdd(&cnt[src[e]], 1);
}

__global__ __launch_bounds__(256) void k_scan1(const int* __restrict__ in, int* __restrict__ out,
                                               int* __restrict__ bsums, int n){
  __shared__ int lds[256];
  const int tid = threadIdx.x;
  const int base = blockIdx.x*1024 + tid*4;
  int v0=0,v1=0,v2=0,v3=0;
  if (base+3 < n){ int4 t = *(const int4*)(in+base); v0=t.x;v1=t.y;v2=t.z;v3=t.w; }
  else {
    if (base   < n) v0 = in[base];
    if (base+1 < n) v1 = in[base+1];
    if (base+2 < n) v2 = in[base+2];
    if (base+3 < n) v3 = in[base+3];
  }
  v0=(v0+3)&~3; v1=(v1+3)&~3; v2=(v2+3)&~3; v3=(v3+3)&~3;  // pad
  int s = v0+v1+v2+v3;
  lds[tid] = s; __syncthreads();
  for (int off=1; off<256; off<<=1){
    int add = (tid>=off)? lds[tid-off] : 0;
    __syncthreads();
    lds[tid] += add;
    __syncthreads();
  }
  int excl = lds[tid] - s;
  if (base   < n) out[base]   = excl;
  if (base+1 < n) out[base+1] = excl+v0;
  if (base+2 < n) out[base+2] = excl+v0+v1;
  if (base+3 < n) out[base+3] = excl+v0+v1+v2;
  if (tid==255) bsums[blockIdx.x] = lds[255];
}

__global__ void k_scan2(int* __restrict__ bs, int nb){
  int tid = threadIdx.x;
  int v = (tid<nb)? bs[tid] : 0;
  int orig = v;
  for (int off=1; off<64; off<<=1){
    int y = __shfl_up(v, off, 64);
    if (tid>=off) v += y;
  }
  if (tid<nb) bs[tid] = v - orig;   // exclusive block offsets
}

__global__ __launch_bounds__(256) void k_scan3(int* __restrict__ rp, int* __restrict__ cursor,
                                               const int* __restrict__ bs, int n){
  const int tid = threadIdx.x;
  const int base = blockIdx.x*1024 + tid*4;
  const int o = bs[blockIdx.x];
#pragma unroll
  for (int j=0;j<4;j++){
    int idx = base+j;
    if (idx < n){ int v = rp[idx]+o; rp[idx]=v; cursor[idx]=v; }
  }
}

__global__ void k_padfill(const int* __restrict__ cnt, const int* __restrict__ rp,
                          int* __restrict__ col){
  int n = blockIdx.x*256 + threadIdx.x;
  if (n < NN){
    int b = rp[n] + cnt[n], e = rp[n+1];
    for (int i=b;i<e;i++) col[i] = NN;   // sentinel: eAr=0, t row = 0
  }
}

__global__ void k_scatter(const int* __restrict__ src, const int* __restrict__ dst,
                          int* __restrict__ cursor, int* __restrict__ col, int E){
  int e = blockIdx.x*256 + threadIdx.x;
  if (e < E){
    int s = src[e];
    int p = atomicAdd(&cursor[s], 1);
    col[p] = dst[e];
  }
}

// ---------------- softmax-denominator + weighted gather + elu, unroll-4
__device__ __forceinline__ void accum(const uint4 p, const float w, float* a){
  a[0] += w*__uint_as_float(p.x<<16); a[1] += w*__uint_as_float(p.x&0xffff0000u);
  a[2] += w*__uint_as_float(p.y<<16); a[3] += w*__uint_as_float(p.y&0xffff0000u);
  a[4] += w*__uint_as_float(p.z<<16); a[5] += w*__uint_as_float(p.z&0xffff0000u);
  a[6] += w*__uint_as_float(p.w<<16); a[7] += w*__uint_as_float(p.w&0xffff0000u);
}

__global__ __launch_bounds__(256) void k_aggr(const int* __restrict__ row_ptr,
                                              const int* __restrict__ col,
                                              const unsigned short* __restrict__ tb,
                                              const float* __restrict__ eAr,
                                              float* __restrict__ out){
  const int tid = threadIdx.x, l = tid&63;
  const long n = (long)blockIdx.x*4 + (tid>>6);
  if (n >= NN) return;
  const int h = l>>3;
  const int beg = row_ptr[n], end = row_ptr[n+1];
  float a[8] = {0,0,0,0,0,0,0,0};
  float den = 0.f;
  for (int i=beg; i<end; i+=4){
    int4 d4 = *(const int4*)(col + i);
    float w0 = eAr[(long)d4.x*NH + h];
    float w1 = eAr[(long)d4.y*NH + h];
    float w2 = eAr[(long)d4.z*NH + h];
    float w3 = eAr[(long)d4.w*NH + h];
    uint4 p0 = *(const uint4*)(tb + (long)d4.x*NC + l*8);
    uint4 p1 = *(const uint4*)(tb + (long)d4.y*NC + l*8);
    uint4 p2 = *(const uint4*)(tb + (long)d4.z*NC + l*8);
    uint4 p3 = *(const uint4*)(tb + (long)d4.w*NC + l*8);
    den += (w0+w1)+(w2+w3);
    accum(p0,w0,a); accum(p1,w1,a); accum(p2,w2,a); accum(p3,w3,a);
  }
  float inv = den>0.f ? 1.f/den : 0.f;
  float4 o0, o1; float v;
  v=a[0]*inv; o0.x = v>0.f? v : expm1f(v);
  v=a[1]*inv; o0.y = v>0.f? v : expm1f(v);
  v=a[2]*inv; o0.z = v>0.f? v : expm1f(v);
  v=a[3]*inv; o0.w = v>0.f? v : expm1f(v);
  v=a[4]*inv; o1.x = v>0.f? v : expm1f(v);
  v=a[5]*inv; o1.y = v>0.f? v : expm1f(v);
  v=a[6]*inv; o1.z = v>0.f? v : expm1f(v);
  v=a[7]*inv; o1.w = v>0.f? v : expm1f(v);
  float* orow = out + n*NC + l*8;
  *(float4*)orow     = o0;
  *(float4*)(orow+4) = o1;
}

extern "C" void kernel_launch(void* const* d_in, const int* in_sizes, int n_in,
                              void* d_out, int out_size, void* d_ws, size_t ws_size,
                              hipStream_t stream){
  const float* x   = (const float*)d_in[0];
  const int*   src = (const int*)d_in[1];
  const int*   dst = (const int*)d_in[2];
  const float* Ws  = (const float*)d_in[3];
  const float* Av  = (const float*)d_in[4];
  const int E = in_sizes[1];

  char* ws = (char*)d_ws;
  size_t off = 0;
  auto alloc = [&](size_t bytes)->void*{
    void* p = ws + off; off += (bytes + 255) & ~(size_t)255; return p;
  };
  unsigned short* tb   = (unsigned short*)alloc((size_t)NROWS*NC*2);
  unsigned short* xs   = (unsigned short*)alloc((size_t)782*32768);
  unsigned short* Wt   = (unsigned short*)alloc((size_t)8*32768);
  float* eAr           = (float*)alloc((size_t)NROWS*NH*4);
  int*   cnt           = (int*)alloc(50304*4);
  int*   row_ptr       = (int*)alloc(50304*4);
  int*   cursor        = (int*)alloc(50304*4);
  int*   bsums         = (int*)alloc(64*4);
  int*   col           = (int*)alloc(((size_t)E + 3*NN + 16)*4);

  hipMemsetAsync(cnt, 0, 50304*4, stream);

  k_prep_x<<<782,256,0,stream>>>(x, xs);
  k_prep_w<<<8,256,0,stream>>>(Ws, Wt);
  k_hist<<<(E+255)/256,256,0,stream>>>(src, cnt, E);
  k_scan1<<<49,256,0,stream>>>(cnt, row_ptr, bsums, NN+1);
  k_scan2<<<1,64,0,stream>>>(bsums, 49);
  k_scan3<<<49,256,0,stream>>>(row_ptr, cursor, bsums, NN+1);
  k_padfill<<<196,256,0,stream>>>(cnt, row_ptr, col);
  k_scatter<<<(E+255)/256,256,0,stream>>>(src, dst, cursor, col, E);
  k_gemm<<<782,256,0,stream>>>(xs, Wt, Av, tb, eAr);
  k_aggr<<<12500,256,0,stream>>>(row_ptr, col, tb, eAr, (float*)d_out);
}

// Round 3
// 553.420 us; speedup vs baseline: 1.1617x; 1.1272x over previous
//
#include <hip/hip_runtime.h>
#include <hip/hip_bf16.h>

#define NN 50000
#define INF 256
#define NH 8
#define OUTF 64
#define NC 512
#define NTILES 782          // ceil(50000/64)
#define CHUNK_TILES 196     // 4 chunks

typedef __attribute__((ext_vector_type(8))) short bf16x8;
typedef __attribute__((ext_vector_type(4))) float f32x4;

__device__ __forceinline__ unsigned short f2bf(float f){
  unsigned u = __float_as_uint(f);
  u += 0x7FFFu + ((u>>16)&1u);
  return (unsigned short)(u>>16);
}

#define GLOAD_LDS16(g, s) \
  __builtin_amdgcn_global_load_lds((const __attribute__((address_space(1))) void*)(g), \
                                   (__attribute__((address_space(3))) void*)(s), 16, 0, 0)

// ---------- W -> per-head swizzled bf16 tiles (64 rows x 256 K)
__global__ __launch_bounds__(256) void k_prep_w(const float* __restrict__ W,
                                                unsigned short* __restrict__ Wt){
  const int tid = threadIdx.x;
  const int r = tid>>2, cb = (tid&3)*64;
  char* tile = (char*)(Wt + (size_t)blockIdx.x*16384);
  const float* Wr = W + ((long)blockIdx.x*64 + r)*INF;
#pragma unroll
  for (int i=0;i<16;i++){
    int c = cb + i*4;
    float4 v = *(const float4*)(Wr + c);
    ushort4 b; b.x=f2bf(v.x); b.y=f2bf(v.y); b.z=f2bf(v.z); b.w=f2bf(v.w);
    int addr = r*512 + ((((c>>3) ^ (r&7)))<<4) + ((c&7)<<1);
    *(ushort4*)(tile + addr) = b;
  }
}

// ---------- atil[h][f] = sum_o W[h*64+o][f] * a_r[h][o]
__global__ void k_atil(const float* __restrict__ W, const float* __restrict__ As,
                       float* __restrict__ atil){
  const int h = blockIdx.x, f = threadIdx.x;
  float s = 0.f;
  for (int o=0;o<64;o++) s += W[((long)h*64+o)*INF + f] * As[h*128 + 64 + o];
  atil[h*256 + f] = s;
}

// ---------- per node: xb (bf16 row) + eAr[n][h] = exp(x[n].atil[h])
__global__ __launch_bounds__(256) void k_xbar(const float* __restrict__ x,
                                              const float* __restrict__ atil,
                                              unsigned short* __restrict__ xb,
                                              float* __restrict__ eAr){
  const int tid = threadIdx.x, w = tid>>6, l = tid&63;
  const long n = (long)blockIdx.x*4 + w;
  if (n > NN) return;
  if (n == NN){   // zero sentinel row
    uint2 z; z.x=0; z.y=0;
    *(uint2*)((char*)xb + (size_t)n*512 + l*8) = z;
    if (l < 8) eAr[n*NH + l] = 0.f;
    return;
  }
  float4 v = *(const float4*)(x + n*INF + l*4);
  uint2 d;
  d.x = (unsigned)f2bf(v.x) | ((unsigned)f2bf(v.y)<<16);
  d.y = (unsigned)f2bf(v.z) | ((unsigned)f2bf(v.w)<<16);
  *(uint2*)((char*)xb + (size_t)n*512 + l*8) = d;
  float p[8];
#pragma unroll
  for (int h=0;h<8;h++){
    float4 a = *(const float4*)(atil + h*256 + l*4);
    p[h] = v.x*a.x + v.y*a.y + v.z*a.z + v.w*a.w;
  }
#pragma unroll
  for (int off=1; off<64; off<<=1){
#pragma unroll
    for (int h=0;h<8;h++) p[h] += __shfl_xor(p[h], off, 64);
  }
  if (l < 8){
    float e = p[0];
#pragma unroll
    for (int h=1;h<8;h++) if (l==h) e = p[h];
    eAr[n*NH + l] = __expf(e);
  }
}

// ---------------- CSR build (counts padded to multiples of 4)
__global__ void k_hist(const int* __restrict__ src, int* __restrict__ cnt, int E){
  int e = blockIdx.x*256 + threadIdx.x;
  if (e < E) atomicAdd(&cnt[src[e]], 1);
}

__global__ __launch_bounds__(256) void k_scan1(const int* __restrict__ in, int* __restrict__ out,
                                               int* __restrict__ bsums, int n){
  __shared__ int lds[256];
  const int tid = threadIdx.x;
  const int base = blockIdx.x*1024 + tid*4;
  int v0=0,v1=0,v2=0,v3=0;
  if (base+3 < n){ int4 t = *(const int4*)(in+base); v0=t.x;v1=t.y;v2=t.z;v3=t.w; }
  else {
    if (base   < n) v0 = in[base];
    if (base+1 < n) v1 = in[base+1];
    if (base+2 < n) v2 = in[base+2];
    if (base+3 < n) v3 = in[base+3];
  }
  v0=(v0+3)&~3; v1=(v1+3)&~3; v2=(v2+3)&~3; v3=(v3+3)&~3;
  int s = v0+v1+v2+v3;
  lds[tid] = s; __syncthreads();
  for (int off=1; off<256; off<<=1){
    int add = (tid>=off)? lds[tid-off] : 0;
    __syncthreads();
    lds[tid] += add;
    __syncthreads();
  }
  int excl = lds[tid] - s;
  if (base   < n) out[base]   = excl;
  if (base+1 < n) out[base+1] = excl+v0;
  if (base+2 < n) out[base+2] = excl+v0+v1;
  if (base+3 < n) out[base+3] = excl+v0+v1+v2;
  if (tid==255) bsums[blockIdx.x] = lds[255];
}

__global__ void k_scan2(int* __restrict__ bs, int nb){
  int tid = threadIdx.x;
  int v = (tid<nb)? bs[tid] : 0;
  int orig = v;
  for (int off=1; off<64; off<<=1){
    int y = __shfl_up(v, off, 64);
    if (tid>=off) v += y;
  }
  if (tid<nb) bs[tid] = v - orig;
}

__global__ __launch_bounds__(256) void k_scan3(int* __restrict__ rp, int* __restrict__ cursor,
                                               const int* __restrict__ bs, int n){
  const int tid = threadIdx.x;
  const int base = blockIdx.x*1024 + tid*4;
  const int o = bs[blockIdx.x];
#pragma unroll
  for (int j=0;j<4;j++){
    int idx = base+j;
    if (idx < n){ int v = rp[idx]+o; rp[idx]=v; cursor[idx]=v; }
  }
}

__global__ void k_padfill(const int* __restrict__ cnt, const int* __restrict__ rp,
                          int* __restrict__ col){
  int n = blockIdx.x*256 + threadIdx.x;
  if (n < NN){
    int b = rp[n] + cnt[n], e = rp[n+1];
    for (int i=b;i<e;i++) col[i] = NN;
  }
}

__global__ void k_scatter(const int* __restrict__ src, const int* __restrict__ dst,
                          int* __restrict__ cursor, int* __restrict__ col, int E){
  int e = blockIdx.x*256 + threadIdx.x;
  if (e < E){
    int s = src[e];
    int p = atomicAdd(&cursor[s], 1);
    col[p] = dst[e];
  }
}

// ---------------- aggregation: g[n,h,0:256] = sum_e w_he * xb[d_e], den
__global__ __launch_bounds__(256) void k_aggr2(const int* __restrict__ row_ptr,
                                               const int* __restrict__ col,
                                               const unsigned short* __restrict__ xb,
                                               const float* __restrict__ eAr,
                                               unsigned short* __restrict__ g,
                                               float* __restrict__ den,
                                               int tile0){
  const int tid = threadIdx.x, l = tid&63;
  const long n = (long)tile0*64 + blockIdx.x*4 + (tid>>6);
  if (n >= NN) return;
  const int beg = row_ptr[n], end = row_ptr[n+1];
  const char* xbp = (const char*)xb;
  float acc[8][4] = {};
  float dn[8] = {0,0,0,0,0,0,0,0};
  const int sel = (l>>3)&3;
  const long l8 = l*8;
  for (int i=beg; i<end; i+=4){
    int4 d4 = *(const int4*)(col + i);
    int dd = sel==0 ? d4.x : sel==1 ? d4.y : sel==2 ? d4.z : d4.w;
    float wv = eAr[(long)dd*NH + (l&7)];
    uint2 p0 = *(const uint2*)(xbp + (size_t)d4.x*512 + l8);
    uint2 p1 = *(const uint2*)(xbp + (size_t)d4.y*512 + l8);
    uint2 p2 = *(const uint2*)(xbp + (size_t)d4.z*512 + l8);
    uint2 p3 = *(const uint2*)(xbp + (size_t)d4.w*512 + l8);
#pragma unroll
    for (int e=0;e<4;e++){
      uint2 pe = (e==0)?p0 : (e==1)?p1 : (e==2)?p2 : p3;
      float f0 = __uint_as_float(pe.x<<16);
      float f1 = __uint_as_float(pe.x&0xffff0000u);
      float f2 = __uint_as_float(pe.y<<16);
      float f3 = __uint_as_float(pe.y&0xffff0000u);
#pragma unroll
      for (int h=0;h<8;h++){
        float w = __shfl(wv, e*8+h, 64);
        dn[h] += w;
        acc[h][0] += w*f0; acc[h][1] += w*f1;
        acc[h][2] += w*f2; acc[h][3] += w*f3;
      }
    }
  }
  // write g row (pre-swizzled bf16 tile image) + den
  const int lt = (int)(n>>6) - tile0;     // local tile
  const int r  = (int)(n&63);
  char* tb = (char*)g + (size_t)lt*262144 + r*512
           + ((((l>>1) ^ (r&7)))<<4) + ((l&1)<<3);
#pragma unroll
  for (int h=0;h<8;h++){
    uint2 d;
    d.x = (unsigned)f2bf(acc[h][0]) | ((unsigned)f2bf(acc[h][1])<<16);
    d.y = (unsigned)f2bf(acc[h][2]) | ((unsigned)f2bf(acc[h][3])<<16);
    *(uint2*)(tb + h*32768) = d;
  }
#pragma unroll
  for (int h=0;h<8;h++) if (l==h) den[n*NH + h] = dn[h];
}

// ---------------- per-head GEMM: out[n, h*64+o] = elu( (g_h[n] . W_h[o]) / den )
__global__ __launch_bounds__(256) void k_gemm2(const unsigned short* __restrict__ g,
                                               const unsigned short* __restrict__ Wt,
                                               const float* __restrict__ den,
                                               float* __restrict__ out,
                                               int tile0){
  __shared__ unsigned short As[16384];
  __shared__ unsigned short Bs[16384];
  __shared__ float linv[64];
  const int tid = threadIdx.x, w = tid>>6, l = tid&63;
  const int brow = tile0 + blockIdx.x;
  const int h = blockIdx.y;
  {
    const char* srcA = (const char*)g + (size_t)blockIdx.x*262144 + h*32768 + w*8192 + l*16;
    char* dstA = (char*)As + w*8192;
#pragma unroll
    for (int k=0;k<8;k++) GLOAD_LDS16(srcA + k*1024, dstA + k*1024);
    const char* srcB = (const char*)Wt + (size_t)h*32768 + w*8192 + l*16;
    char* dstB = (char*)Bs + w*8192;
#pragma unroll
    for (int k=0;k<8;k++) GLOAD_LDS16(srcB + k*1024, dstB + k*1024);
  }
  if (tid < 64){
    long gr = (long)brow*64 + tid;
    float dv = (gr < NN) ? den[gr*NH + h] : 1.f;
    linv[tid] = dv > 0.f ? 1.f/dv : 0.f;
  }
  asm volatile("s_waitcnt vmcnt(0)");
  __syncthreads();

  const int col = w*16 + (l&15);
  f32x4 acc[4] = {};
#pragma unroll
  for (int ks=0; ks<8; ks++){
    int chunkB = (ks*4 + (l>>4)) ^ (col&7);
    bf16x8 bfrag = *(const bf16x8*)((char*)Bs + col*512 + (chunkB<<4));
#pragma unroll
    for (int mt=0; mt<4; mt++){
      int ar_ = mt*16 + (l&15);
      int chunkA = (ks*4 + (l>>4)) ^ (ar_&7);
      bf16x8 afrag = *(const bf16x8*)((char*)As + ar_*512 + (chunkA<<4));
      acc[mt] = __builtin_amdgcn_mfma_f32_16x16x32_bf16(afrag, bfrag, acc[mt], 0,0,0);
    }
  }
#pragma unroll
  for (int mt=0; mt<4; mt++){
#pragma unroll
    for (int j=0;j<4;j++){
      int r = mt*16 + (l>>4)*4 + j;
      long gr = (long)brow*64 + r;
      if (gr < NN){
        float v = acc[mt][j] * linv[r];
        out[gr*NC + h*64 + col] = v>0.f ? v : expm1f(v);
      }
    }
  }
}

extern "C" void kernel_launch(void* const* d_in, const int* in_sizes, int n_in,
                              void* d_out, int out_size, void* d_ws, size_t ws_size,
                              hipStream_t stream){
  const float* x   = (const float*)d_in[0];
  const int*   src = (const int*)d_in[1];
  const int*   dst = (const int*)d_in[2];
  const float* Ws  = (const float*)d_in[3];
  const float* Av  = (const float*)d_in[4];
  const int E = in_sizes[1];

  char* ws = (char*)d_ws;
  size_t off = 0;
  auto alloc = [&](size_t bytes)->void*{
    void* p = ws + off; off += (bytes + 255) & ~(size_t)255; return p;
  };
  unsigned short* xb   = (unsigned short*)alloc((size_t)50048*512);   // bf16 rows (incl sentinel)
  float* eAr           = (float*)alloc((size_t)50048*NH*4);
  float* atil          = (float*)alloc(8*256*4);
  float* den           = (float*)alloc((size_t)50048*NH*4);
  unsigned short* Wt   = (unsigned short*)alloc((size_t)8*32768);
  int*   cnt           = (int*)alloc(50304*4);
  int*   row_ptr       = (int*)alloc(50304*4);
  int*   cursor        = (int*)alloc(50304*4);
  int*   bsums         = (int*)alloc(64*4);
  int*   col           = (int*)alloc(((size_t)E + 3*NN + 16)*4);
  unsigned short* g    = (unsigned short*)alloc((size_t)CHUNK_TILES*262144);

  hipMemsetAsync(cnt, 0, 50304*4, stream);

  k_prep_w<<<8,256,0,stream>>>(Ws, Wt);
  k_atil<<<8,256,0,stream>>>(Ws, Av, atil);
  k_xbar<<<12501,256,0,stream>>>(x, atil, xb, eAr);
  k_hist<<<(E+255)/256,256,0,stream>>>(src, cnt, E);
  k_scan1<<<49,256,0,stream>>>(cnt, row_ptr, bsums, NN+1);
  k_scan2<<<1,64,0,stream>>>(bsums, 49);
  k_scan3<<<49,256,0,stream>>>(row_ptr, cursor, bsums, NN+1);
  k_padfill<<<196,256,0,stream>>>(cnt, row_ptr, col);
  k_scatter<<<(E+255)/256,256,0,stream>>>(src, dst, cursor, col, E);

  int tile0 = 0;
  while (tile0 < NTILES){
    int tiles = NTILES - tile0 < CHUNK_TILES ? NTILES - tile0 : CHUNK_TILES;
    k_aggr2<<<tiles*16,256,0,stream>>>(row_ptr, col, xb, eAr, g, den, tile0);
    k_gemm2<<<dim3(tiles,8),256,0,stream>>>(g, Wt, den, (float*)d_out, tile0);
    tile0 += tiles;
  }
}

// Round 4
// 412.387 us; speedup vs baseline: 1.5590x; 1.3420x over previous
//
#include <hip/hip_runtime.h>
#include <hip/hip_bf16.h>

#define NN 50000
#define INF 256
#define NH 8
#define OUTF 64
#define NC 512
#define NTILES 782          // ceil(50000/64)
#define CHUNK_TILES 196     // 4 chunks
#define EPB 8192            // edges per sort block
#define NBK 391             // buckets: node>>7, 50000/128

typedef __attribute__((ext_vector_type(8))) short bf16x8;
typedef __attribute__((ext_vector_type(4))) float f32x4;

__device__ __forceinline__ unsigned short f2bf(float f){
  unsigned u = __float_as_uint(f);
  u += 0x7FFFu + ((u>>16)&1u);
  return (unsigned short)(u>>16);
}

#define GLOAD_LDS16(g, s) \
  __builtin_amdgcn_global_load_lds((const __attribute__((address_space(1))) void*)(g), \
                                   (__attribute__((address_space(3))) void*)(s), 16, 0, 0)

// ---------- W -> per-head swizzled bf16 tiles (64 rows x 256 K)
__global__ __launch_bounds__(256) void k_prep_w(const float* __restrict__ W,
                                                unsigned short* __restrict__ Wt){
  const int tid = threadIdx.x;
  const int r = tid>>2, cb = (tid&3)*64;
  char* tile = (char*)(Wt + (size_t)blockIdx.x*16384);
  const float* Wr = W + ((long)blockIdx.x*64 + r)*INF;
#pragma unroll
  for (int i=0;i<16;i++){
    int c = cb + i*4;
    float4 v = *(const float4*)(Wr + c);
    ushort4 b; b.x=f2bf(v.x); b.y=f2bf(v.y); b.z=f2bf(v.z); b.w=f2bf(v.w);
    int addr = r*512 + ((((c>>3) ^ (r&7)))<<4) + ((c&7)<<1);
    *(ushort4*)(tile + addr) = b;
  }
}

// ---------- atil[h][f] = sum_o W[h*64+o][f] * a_r[h][o]
__global__ void k_atil(const float* __restrict__ W, const float* __restrict__ As,
                       float* __restrict__ atil){
  const int h = blockIdx.x, f = threadIdx.x;
  float s = 0.f;
  for (int o=0;o<64;o++) s += W[((long)h*64+o)*INF + f] * As[h*128 + 64 + o];
  atil[h*256 + f] = s;
}

// ---------- per node: xb (bf16 row) + eAr[n][h] = exp(x[n].atil[h])
__global__ __launch_bounds__(256) void k_xbar(const float* __restrict__ x,
                                              const float* __restrict__ atil,
                                              unsigned short* __restrict__ xb,
                                              float* __restrict__ eAr){
  const int tid = threadIdx.x, w = tid>>6, l = tid&63;
  const long n = (long)blockIdx.x*4 + w;
  if (n > NN) return;
  if (n == NN){   // zero sentinel row
    uint2 z; z.x=0; z.y=0;
    *(uint2*)((char*)xb + (size_t)n*512 + l*8) = z;
    if (l < 8) eAr[n*NH + l] = 0.f;
    return;
  }
  float4 v = *(const float4*)(x + n*INF + l*4);
  uint2 d;
  d.x = (unsigned)f2bf(v.x) | ((unsigned)f2bf(v.y)<<16);
  d.y = (unsigned)f2bf(v.z) | ((unsigned)f2bf(v.w)<<16);
  *(uint2*)((char*)xb + (size_t)n*512 + l*8) = d;
  float p[8];
#pragma unroll
  for (int h=0;h<8;h++){
    float4 a = *(const float4*)(atil + h*256 + l*4);
    p[h] = v.x*a.x + v.y*a.y + v.z*a.z + v.w*a.w;
  }
#pragma unroll
  for (int off=1; off<64; off<<=1){
#pragma unroll
    for (int h=0;h<8;h++) p[h] += __shfl_xor(p[h], off, 64);
  }
  if (l < 8){
    float e = p[0];
#pragma unroll
    for (int h=1;h<8;h++) if (l==h) e = p[h];
    eAr[n*NH + l] = __expf(e);
  }
}

// ---------------- CSR build: bucketed counting sort, no global atomics
// K1: per-block bucket histogram -> M[k][b] (column-major per bucket)
__global__ __launch_bounds__(256) void k_bhist(const int* __restrict__ src,
                                               int* __restrict__ M, int E, int NB){
  __shared__ int h[NBK];
  const int tid = threadIdx.x, b = blockIdx.x;
  for (int i=tid;i<NBK;i+=256) h[i]=0;
  __syncthreads();
  const int base = b*EPB;
  const int lim = min(E-base, EPB);
  for (int i=tid;i<lim;i+=256) atomicAdd(&h[src[base+i]>>7], 1);
  __syncthreads();
  for (int i=tid;i<NBK;i+=256) M[(long)i*NB + b] = h[i];
}

// K2a: per-bucket exclusive scan over blocks (in place) + bucket totals
__global__ __launch_bounds__(256) void k_bscan(int* __restrict__ M,
                                               int* __restrict__ tot, int NB){
  __shared__ int lds[256];
  const int k = blockIdx.x, tid = threadIdx.x;
  int v = (tid<NB) ? M[(long)k*NB+tid] : 0;
  const int orig = v;
  lds[tid]=v; __syncthreads();
  for (int off=1; off<256; off<<=1){
    int a = (tid>=off)? lds[tid-off] : 0;
    __syncthreads(); lds[tid]+=a; __syncthreads();
  }
  if (tid<NB) M[(long)k*NB+tid] = lds[tid]-orig;
  if (tid==255) tot[k] = lds[255];
}

// K2b: exclusive scan of bucket totals -> bOff[0..NBK]
__global__ __launch_bounds__(512) void k_bscan2(const int* __restrict__ tot,
                                                int* __restrict__ bOff){
  __shared__ int lds[512];
  const int tid = threadIdx.x;
  int v = (tid<NBK)? tot[tid] : 0;
  const int orig = v;
  lds[tid]=v; __syncthreads();
  for (int off=1; off<512; off<<=1){
    int a = (tid>=off)? lds[tid-off] : 0;
    __syncthreads(); lds[tid]+=a; __syncthreads();
  }
  if (tid<=NBK) bOff[tid] = lds[tid]-orig;
}

// K3: bucket scatter of (src,dst) pairs via LDS cursors
__global__ __launch_bounds__(256) void k_bscat(const int* __restrict__ src,
                                               const int* __restrict__ dst,
                                               const int* __restrict__ M,
                                               const int* __restrict__ bOff,
                                               unsigned long long* __restrict__ ebuf,
                                               int E, int NB){
  __shared__ int cur[NBK];
  const int tid = threadIdx.x, b = blockIdx.x;
  for (int i=tid;i<NBK;i+=256) cur[i] = bOff[i] + M[(long)i*NB + b];
  __syncthreads();
  const int base = b*EPB;
  const int lim = min(E-base, EPB);
  for (int i=tid;i<lim;i+=256){
    int s = src[base+i], d = dst[base+i];
    int p = atomicAdd(&cur[s>>7], 1);
    ebuf[p] = ((unsigned long long)(unsigned)d<<32) | (unsigned)s;
  }
}

// K4: per-bucket node counts (replaces global-atomic hist)
__global__ __launch_bounds__(256) void k_bcnt(const unsigned long long* __restrict__ ebuf,
                                              const int* __restrict__ bOff,
                                              int* __restrict__ cnt){
  __shared__ int h[128];
  const int k = blockIdx.x, tid = threadIdx.x;
  if (tid<128) h[tid]=0;
  __syncthreads();
  const int beg = bOff[k], end = bOff[k+1];
  for (int i=beg+tid; i<end; i+=256)
    atomicAdd(&h[(int)(unsigned)ebuf[i] & 127], 1);
  __syncthreads();
  if (tid<128) cnt[(k<<7)+tid] = h[tid];
}

__global__ __launch_bounds__(256) void k_scan1(const int* __restrict__ in, int* __restrict__ out,
                                               int* __restrict__ bsums, int n){
  __shared__ int lds[256];
  const int tid = threadIdx.x;
  const int base = blockIdx.x*1024 + tid*4;
  int v0=0,v1=0,v2=0,v3=0;
  if (base+3 < n){ int4 t = *(const int4*)(in+base); v0=t.x;v1=t.y;v2=t.z;v3=t.w; }
  else {
    if (base   < n) v0 = in[base];
    if (base+1 < n) v1 = in[base+1];
    if (base+2 < n) v2 = in[base+2];
    if (base+3 < n) v3 = in[base+3];
  }
  v0=(v0+3)&~3; v1=(v1+3)&~3; v2=(v2+3)&~3; v3=(v3+3)&~3;
  int s = v0+v1+v2+v3;
  lds[tid] = s; __syncthreads();
  for (int off=1; off<256; off<<=1){
    int add = (tid>=off)? lds[tid-off] : 0;
    __syncthreads();
    lds[tid] += add;
    __syncthreads();
  }
  int excl = lds[tid] - s;
  if (base   < n) out[base]   = excl;
  if (base+1 < n) out[base+1] = excl+v0;
  if (base+2 < n) out[base+2] = excl+v0+v1;
  if (base+3 < n) out[base+3] = excl+v0+v1+v2;
  if (tid==255) bsums[blockIdx.x] = lds[255];
}

__global__ void k_scan2(int* __restrict__ bs, int nb){
  int tid = threadIdx.x;
  int v = (tid<nb)? bs[tid] : 0;
  int orig = v;
  for (int off=1; off<64; off<<=1){
    int y = __shfl_up(v, off, 64);
    if (tid>=off) v += y;
  }
  if (tid<nb) bs[tid] = v - orig;
}

__global__ __launch_bounds__(256) void k_scan3(int* __restrict__ rp,
                                               const int* __restrict__ bs, int n){
  const int tid = threadIdx.x;
  const int base = blockIdx.x*1024 + tid*4;
  const int o = bs[blockIdx.x];
#pragma unroll
  for (int j=0;j<4;j++){
    int idx = base+j;
    if (idx < n) rp[idx] += o;
  }
}

__global__ void k_padfill(const int* __restrict__ cnt, const int* __restrict__ rp,
                          int* __restrict__ col){
  int n = blockIdx.x*256 + threadIdx.x;
  if (n < NN){
    int b = rp[n] + cnt[n], e = rp[n+1];
    for (int i=b;i<e;i++) col[i] = NN;
  }
}

// K8: final per-bucket scatter into CSR col, LDS cursors, localized writes
__global__ __launch_bounds__(256) void k_fscat(const unsigned long long* __restrict__ ebuf,
                                               const int* __restrict__ bOff,
                                               const int* __restrict__ rp,
                                               int* __restrict__ col){
  __shared__ int cur[128];
  const int k = blockIdx.x, tid = threadIdx.x;
  if (tid<128) cur[tid] = rp[min((k<<7)+tid, NN)];
  __syncthreads();
  const int beg = bOff[k], end = bOff[k+1];
  for (int i=beg+tid; i<end; i+=256){
    unsigned long long e = ebuf[i];
    int s = (int)(unsigned)e;
    int d = (int)(e>>32);
    int p = atomicAdd(&cur[s&127], 1);
    col[p] = d;
  }
}

// ---------------- aggregation: g[n,h,0:256] = sum_e w_he * xb[d_e], den
__global__ __launch_bounds__(256) void k_aggr2(const int* __restrict__ row_ptr,
                                               const int* __restrict__ col,
                                               const unsigned short* __restrict__ xb,
                                               const float* __restrict__ eAr,
                                               unsigned short* __restrict__ g,
                                               float* __restrict__ den,
                                               int tile0){
  const int tid = threadIdx.x, l = tid&63;
  const long n = (long)tile0*64 + blockIdx.x*4 + (tid>>6);
  if (n >= NN) return;
  const int beg = row_ptr[n], end = row_ptr[n+1];
  const char* xbp = (const char*)xb;
  float acc[8][4] = {};
  float dn[8] = {0,0,0,0,0,0,0,0};
  const int sel = (l>>3)&3;
  const long l8 = l*8;
  for (int i=beg; i<end; i+=4){
    int4 d4 = *(const int4*)(col + i);
    int dd = sel==0 ? d4.x : sel==1 ? d4.y : sel==2 ? d4.z : d4.w;
    float wv = eAr[(long)dd*NH + (l&7)];
    uint2 p0 = *(const uint2*)(xbp + (size_t)d4.x*512 + l8);
    uint2 p1 = *(const uint2*)(xbp + (size_t)d4.y*512 + l8);
    uint2 p2 = *(const uint2*)(xbp + (size_t)d4.z*512 + l8);
    uint2 p3 = *(const uint2*)(xbp + (size_t)d4.w*512 + l8);
#pragma unroll
    for (int e=0;e<4;e++){
      uint2 pe = (e==0)?p0 : (e==1)?p1 : (e==2)?p2 : p3;
      float f0 = __uint_as_float(pe.x<<16);
      float f1 = __uint_as_float(pe.x&0xffff0000u);
      float f2 = __uint_as_float(pe.y<<16);
      float f3 = __uint_as_float(pe.y&0xffff0000u);
#pragma unroll
      for (int h=0;h<8;h++){
        float w = __shfl(wv, e*8+h, 64);
        dn[h] += w;
        acc[h][0] += w*f0; acc[h][1] += w*f1;
        acc[h][2] += w*f2; acc[h][3] += w*f3;
      }
    }
  }
  const int lt = (int)(n>>6) - tile0;
  const int r  = (int)(n&63);
  char* tb = (char*)g + (size_t)lt*262144 + r*512
           + ((((l>>1) ^ (r&7)))<<4) + ((l&1)<<3);
#pragma unroll
  for (int h=0;h<8;h++){
    uint2 d;
    d.x = (unsigned)f2bf(acc[h][0]) | ((unsigned)f2bf(acc[h][1])<<16);
    d.y = (unsigned)f2bf(acc[h][2]) | ((unsigned)f2bf(acc[h][3])<<16);
    *(uint2*)(tb + h*32768) = d;
  }
#pragma unroll
  for (int h=0;h<8;h++) if (l==h) den[n*NH + h] = dn[h];
}

// ---------------- per-head GEMM: out[n, h*64+o] = elu( (g_h[n] . W_h[o]) / den )
__global__ __launch_bounds__(256) void k_gemm2(const unsigned short* __restrict__ g,
                                               const unsigned short* __restrict__ Wt,
                                               const float* __restrict__ den,
                                               float* __restrict__ out,
                                               int tile0){
  __shared__ unsigned short As[16384];
  __shared__ unsigned short Bs[16384];
  __shared__ float linv[64];
  const int tid = threadIdx.x, w = tid>>6, l = tid&63;
  const int brow = tile0 + blockIdx.x;
  const int h = blockIdx.y;
  {
    const char* srcA = (const char*)g + (size_t)blockIdx.x*262144 + h*32768 + w*8192 + l*16;
    char* dstA = (char*)As + w*8192;
#pragma unroll
    for (int k=0;k<8;k++) GLOAD_LDS16(srcA + k*1024, dstA + k*1024);
    const char* srcB = (const char*)Wt + (size_t)h*32768 + w*8192 + l*16;
    char* dstB = (char*)Bs + w*8192;
#pragma unroll
    for (int k=0;k<8;k++) GLOAD_LDS16(srcB + k*1024, dstB + k*1024);
  }
  if (tid < 64){
    long gr = (long)brow*64 + tid;
    float dv = (gr < NN) ? den[gr*NH + h] : 1.f;
    linv[tid] = dv > 0.f ? 1.f/dv : 0.f;
  }
  asm volatile("s_waitcnt vmcnt(0)");
  __syncthreads();

  const int col = w*16 + (l&15);
  f32x4 acc[4] = {};
#pragma unroll
  for (int ks=0; ks<8; ks++){
    int chunkB = (ks*4 + (l>>4)) ^ (col&7);
    bf16x8 bfrag = *(const bf16x8*)((char*)Bs + col*512 + (chunkB<<4));
#pragma unroll
    for (int mt=0; mt<4; mt++){
      int ar_ = mt*16 + (l&15);
      int chunkA = (ks*4 + (l>>4)) ^ (ar_&7);
      bf16x8 afrag = *(const bf16x8*)((char*)As + ar_*512 + (chunkA<<4));
      acc[mt] = __builtin_amdgcn_mfma_f32_16x16x32_bf16(afrag, bfrag, acc[mt], 0,0,0);
    }
  }
#pragma unroll
  for (int mt=0; mt<4; mt++){
#pragma unroll
    for (int j=0;j<4;j++){
      int r = mt*16 + (l>>4)*4 + j;
      long gr = (long)brow*64 + r;
      if (gr < NN){
        float v = acc[mt][j] * linv[r];
        out[gr*NC + h*64 + col] = v>0.f ? v : expm1f(v);
      }
    }
  }
}

extern "C" void kernel_launch(void* const* d_in, const int* in_sizes, int n_in,
                              void* d_out, int out_size, void* d_ws, size_t ws_size,
                              hipStream_t stream){
  const float* x   = (const float*)d_in[0];
  const int*   src = (const int*)d_in[1];
  const int*   dst = (const int*)d_in[2];
  const float* Ws  = (const float*)d_in[3];
  const float* Av  = (const float*)d_in[4];
  const int E = in_sizes[1];
  const int NB = (E + EPB - 1) / EPB;   // <=256 for E<=2M

  char* ws = (char*)d_ws;
  size_t off = 0;
  auto alloc = [&](size_t bytes)->void*{
    void* p = ws + off; off += (bytes + 255) & ~(size_t)255; return p;
  };
  unsigned short* xb   = (unsigned short*)alloc((size_t)50048*512);
  float* eAr           = (float*)alloc((size_t)50048*NH*4);
  float* atil          = (float*)alloc(8*256*4);
  float* den           = (float*)alloc((size_t)50048*NH*4);
  unsigned short* Wt   = (unsigned short*)alloc((size_t)8*32768);
  int*   cnt           = (int*)alloc(50304*4);
  int*   row_ptr       = (int*)alloc(50304*4);
  int*   M             = (int*)alloc((size_t)NBK*256*4);
  int*   tot           = (int*)alloc(512*4);
  int*   bOff          = (int*)alloc(512*4);
  int*   bsums         = (int*)alloc(64*4);
  int*   col           = (int*)alloc(((size_t)E + 3*NN + 16)*4);
  unsigned short* g    = (unsigned short*)alloc((size_t)CHUNK_TILES*262144);
  unsigned long long* ebuf = (unsigned long long*)g;   // alias: dead before g is written

  k_prep_w<<<8,256,0,stream>>>(Ws, Wt);
  k_atil<<<8,256,0,stream>>>(Ws, Av, atil);
  k_xbar<<<12501,256,0,stream>>>(x, atil, xb, eAr);

  k_bhist<<<NB,256,0,stream>>>(src, M, E, NB);
  k_bscan<<<NBK,256,0,stream>>>(M, tot, NB);
  k_bscan2<<<1,512,0,stream>>>(tot, bOff);
  k_bscat<<<NB,256,0,stream>>>(src, dst, M, bOff, ebuf, E, NB);
  k_bcnt<<<NBK,256,0,stream>>>(ebuf, bOff, cnt);
  k_scan1<<<49,256,0,stream>>>(cnt, row_ptr, bsums, NN+1);
  k_scan2<<<1,64,0,stream>>>(bsums, 49);
  k_scan3<<<49,256,0,stream>>>(row_ptr, bsums, NN+1);
  k_padfill<<<196,256,0,stream>>>(cnt, row_ptr, col);
  k_fscat<<<NBK,256,0,stream>>>(ebuf, bOff, row_ptr, col);

  int tile0 = 0;
  while (tile0 < NTILES){
    int tiles = NTILES - tile0 < CHUNK_TILES ? NTILES - tile0 : CHUNK_TILES;
    k_aggr2<<<tiles*16,256,0,stream>>>(row_ptr, col, xb, eAr, g, den, tile0);
    k_gemm2<<<dim3(tiles,8),256,0,stream>>>(g, Wt, den, (float*)d_out, tile0);
    tile0 += tiles;
  }
}

// Round 5
// 379.655 us; speedup vs baseline: 1.6935x; 1.0862x over previous
//
#include <hip/hip_runtime.h>
#include <hip/hip_bf16.h>

#define NN 50000
#define INF 256
#define NH 8
#define OUTF 64
#define NC 512
#define NTILES 782          // ceil(50000/64)
#define CHUNK_TILES 196     // 4 chunks
#define EPB 8192            // edges per sort block
#define NBK 391             // buckets: node>>7, 50000/128

typedef __attribute__((ext_vector_type(8))) short bf16x8;
typedef __attribute__((ext_vector_type(4))) float f32x4;

__device__ __forceinline__ unsigned short f2bf(float f){
  unsigned u = __float_as_uint(f);
  u += 0x7FFFu + ((u>>16)&1u);
  return (unsigned short)(u>>16);
}

#define GLOAD_LDS16(g, s) \
  __builtin_amdgcn_global_load_lds((const __attribute__((address_space(1))) void*)(g), \
                                   (__attribute__((address_space(3))) void*)(s), 16, 0, 0)

// ---------- W -> per-head swizzled bf16 tiles (64 rows x 256 K)
__global__ __launch_bounds__(256) void k_prep_w(const float* __restrict__ W,
                                                unsigned short* __restrict__ Wt){
  const int tid = threadIdx.x;
  const int r = tid>>2, cb = (tid&3)*64;
  char* tile = (char*)(Wt + (size_t)blockIdx.x*16384);
  const float* Wr = W + ((long)blockIdx.x*64 + r)*INF;
#pragma unroll
  for (int i=0;i<16;i++){
    int c = cb + i*4;
    float4 v = *(const float4*)(Wr + c);
    ushort4 b; b.x=f2bf(v.x); b.y=f2bf(v.y); b.z=f2bf(v.z); b.w=f2bf(v.w);
    int addr = r*512 + ((((c>>3) ^ (r&7)))<<4) + ((c&7)<<1);
    *(ushort4*)(tile + addr) = b;
  }
}

// ---------- atil[h][f] = sum_o W[h*64+o][f] * a_r[h][o]
__global__ void k_atil(const float* __restrict__ W, const float* __restrict__ As,
                       float* __restrict__ atil){
  const int h = blockIdx.x, f = threadIdx.x;
  float s = 0.f;
  for (int o=0;o<64;o++) s += W[((long)h*64+o)*INF + f] * As[h*128 + 64 + o];
  atil[h*256 + f] = s;
}

// ---------- per node: xb (bf16 row) + eAr[n][h] = exp(x[n].atil[h])
__global__ __launch_bounds__(256) void k_xbar(const float* __restrict__ x,
                                              const float* __restrict__ atil,
                                              unsigned short* __restrict__ xb,
                                              float* __restrict__ eAr){
  const int tid = threadIdx.x, w = tid>>6, l = tid&63;
  const long n = (long)blockIdx.x*4 + w;
  if (n > NN) return;
  if (n == NN){   // zero sentinel row
    uint2 z; z.x=0; z.y=0;
    *(uint2*)((char*)xb + (size_t)n*512 + l*8) = z;
    if (l < 8) eAr[n*NH + l] = 0.f;
    return;
  }
  float4 v = *(const float4*)(x + n*INF + l*4);
  uint2 d;
  d.x = (unsigned)f2bf(v.x) | ((unsigned)f2bf(v.y)<<16);
  d.y = (unsigned)f2bf(v.z) | ((unsigned)f2bf(v.w)<<16);
  *(uint2*)((char*)xb + (size_t)n*512 + l*8) = d;
  float p[8];
#pragma unroll
  for (int h=0;h<8;h++){
    float4 a = *(const float4*)(atil + h*256 + l*4);
    p[h] = v.x*a.x + v.y*a.y + v.z*a.z + v.w*a.w;
  }
#pragma unroll
  for (int off=1; off<64; off<<=1){
#pragma unroll
    for (int h=0;h<8;h++) p[h] += __shfl_xor(p[h], off, 64);
  }
  if (l < 8){
    float e = p[0];
#pragma unroll
    for (int h=1;h<8;h++) if (l==h) e = p[h];
    eAr[n*NH + l] = __expf(e);
  }
}

// ---------------- CSR build: bucketed counting sort, no global atomics
__global__ __launch_bounds__(256) void k_bhist(const int* __restrict__ src,
                                               int* __restrict__ M, int E, int NB){
  __shared__ int h[NBK];
  const int tid = threadIdx.x, b = blockIdx.x;
  for (int i=tid;i<NBK;i+=256) h[i]=0;
  __syncthreads();
  const int base = b*EPB;
  const int lim = min(E-base, EPB);
  for (int i=tid;i<lim;i+=256) atomicAdd(&h[src[base+i]>>7], 1);
  __syncthreads();
  for (int i=tid;i<NBK;i+=256) M[(long)i*NB + b] = h[i];
}

__global__ __launch_bounds__(256) void k_bscan(int* __restrict__ M,
                                               int* __restrict__ tot, int NB){
  __shared__ int lds[256];
  const int k = blockIdx.x, tid = threadIdx.x;
  int v = (tid<NB) ? M[(long)k*NB+tid] : 0;
  const int orig = v;
  lds[tid]=v; __syncthreads();
  for (int off=1; off<256; off<<=1){
    int a = (tid>=off)? lds[tid-off] : 0;
    __syncthreads(); lds[tid]+=a; __syncthreads();
  }
  if (tid<NB) M[(long)k*NB+tid] = lds[tid]-orig;
  if (tid==255) tot[k] = lds[255];
}

__global__ __launch_bounds__(512) void k_bscan2(const int* __restrict__ tot,
                                                int* __restrict__ bOff){
  __shared__ int lds[512];
  const int tid = threadIdx.x;
  int v = (tid<NBK)? tot[tid] : 0;
  const int orig = v;
  lds[tid]=v; __syncthreads();
  for (int off=1; off<512; off<<=1){
    int a = (tid>=off)? lds[tid-off] : 0;
    __syncthreads(); lds[tid]+=a; __syncthreads();
  }
  if (tid<=NBK) bOff[tid] = lds[tid]-orig;
}

__global__ __launch_bounds__(256) void k_bscat(const int* __restrict__ src,
                                               const int* __restrict__ dst,
                                               const int* __restrict__ M,
                                               const int* __restrict__ bOff,
                                               unsigned long long* __restrict__ ebuf,
                                               int E, int NB){
  __shared__ int cur[NBK];
  const int tid = threadIdx.x, b = blockIdx.x;
  for (int i=tid;i<NBK;i+=256) cur[i] = bOff[i] + M[(long)i*NB + b];
  __syncthreads();
  const int base = b*EPB;
  const int lim = min(E-base, EPB);
  for (int i=tid;i<lim;i+=256){
    int s = src[base+i], d = dst[base+i];
    int p = atomicAdd(&cur[s>>7], 1);
    ebuf[p] = ((unsigned long long)(unsigned)d<<32) | (unsigned)s;
  }
}

__global__ __launch_bounds__(256) void k_bcnt(const unsigned long long* __restrict__ ebuf,
                                              const int* __restrict__ bOff,
                                              int* __restrict__ cnt){
  __shared__ int h[128];
  const int k = blockIdx.x, tid = threadIdx.x;
  if (tid<128) h[tid]=0;
  __syncthreads();
  const int beg = bOff[k], end = bOff[k+1];
  for (int i=beg+tid; i<end; i+=256)
    atomicAdd(&h[(int)(unsigned)ebuf[i] & 127], 1);
  __syncthreads();
  if (tid<128) cnt[(k<<7)+tid] = h[tid];
}

__global__ __launch_bounds__(256) void k_scan1(const int* __restrict__ in, int* __restrict__ out,
                                               int* __restrict__ bsums, int n){
  __shared__ int lds[256];
  const int tid = threadIdx.x;
  const int base = blockIdx.x*1024 + tid*4;
  int v0=0,v1=0,v2=0,v3=0;
  if (base+3 < n){ int4 t = *(const int4*)(in+base); v0=t.x;v1=t.y;v2=t.z;v3=t.w; }
  else {
    if (base   < n) v0 = in[base];
    if (base+1 < n) v1 = in[base+1];
    if (base+2 < n) v2 = in[base+2];
    if (base+3 < n) v3 = in[base+3];
  }
  v0=(v0+3)&~3; v1=(v1+3)&~3; v2=(v2+3)&~3; v3=(v3+3)&~3;
  int s = v0+v1+v2+v3;
  lds[tid] = s; __syncthreads();
  for (int off=1; off<256; off<<=1){
    int add = (tid>=off)? lds[tid-off] : 0;
    __syncthreads();
    lds[tid] += add;
    __syncthreads();
  }
  int excl = lds[tid] - s;
  if (base   < n) out[base]   = excl;
  if (base+1 < n) out[base+1] = excl+v0;
  if (base+2 < n) out[base+2] = excl+v0+v1;
  if (base+3 < n) out[base+3] = excl+v0+v1+v2;
  if (tid==255) bsums[blockIdx.x] = lds[255];
}

__global__ void k_scan2(int* __restrict__ bs, int nb){
  int tid = threadIdx.x;
  int v = (tid<nb)? bs[tid] : 0;
  int orig = v;
  for (int off=1; off<64; off<<=1){
    int y = __shfl_up(v, off, 64);
    if (tid>=off) v += y;
  }
  if (tid<nb) bs[tid] = v - orig;
}

__global__ __launch_bounds__(256) void k_scan3(int* __restrict__ rp,
                                               const int* __restrict__ bs, int n){
  const int tid = threadIdx.x;
  const int base = blockIdx.x*1024 + tid*4;
  const int o = bs[blockIdx.x];
#pragma unroll
  for (int j=0;j<4;j++){
    int idx = base+j;
    if (idx < n) rp[idx] += o;
  }
}

__global__ void k_padfill(const int* __restrict__ cnt, const int* __restrict__ rp,
                          int* __restrict__ col){
  int n = blockIdx.x*256 + threadIdx.x;
  if (n < NN){
    int b = rp[n] + cnt[n], e = rp[n+1];
    for (int i=b;i<e;i++) col[i] = NN;
  }
}

__global__ __launch_bounds__(256) void k_fscat(const unsigned long long* __restrict__ ebuf,
                                               const int* __restrict__ bOff,
                                               const int* __restrict__ rp,
                                               int* __restrict__ col){
  __shared__ int cur[128];
  const int k = blockIdx.x, tid = threadIdx.x;
  if (tid<128) cur[tid] = rp[min((k<<7)+tid, NN)];
  __syncthreads();
  const int beg = bOff[k], end = bOff[k+1];
  for (int i=beg+tid; i<end; i+=256){
    unsigned long long e = ebuf[i];
    int s = (int)(unsigned)e;
    int d = (int)(e>>32);
    int p = atomicAdd(&cur[s&127], 1);
    col[p] = d;
  }
}

// ---------------- aggregation: scalar-pipe weights, no cross-lane ops
__global__ __launch_bounds__(256) void k_aggr2(const int* __restrict__ row_ptr,
                                               const int* __restrict__ col,
                                               const unsigned short* __restrict__ xb,
                                               const float* __restrict__ eAr,
                                               unsigned short* __restrict__ g,
                                               float* __restrict__ den,
                                               int tile0){
  const int tid = threadIdx.x, l = tid&63;
  const long n = (long)tile0*64 + blockIdx.x*4 + (tid>>6);
  if (n >= NN) return;
  const int beg = __builtin_amdgcn_readfirstlane(row_ptr[n]);
  const int end = __builtin_amdgcn_readfirstlane(row_ptr[n+1]);
  const char* xbp = (const char*)xb;
  float acc[8][4] = {};
  float dnl = 0.f;
  const long l8 = (long)l*8;
  const int lw = l&7;
  for (int i=beg; i<end; i+=4){
    const int d0 = __builtin_amdgcn_readfirstlane(col[i]);
    const int d1 = __builtin_amdgcn_readfirstlane(col[i+1]);
    const int d2 = __builtin_amdgcn_readfirstlane(col[i+2]);
    const int d3 = __builtin_amdgcn_readfirstlane(col[i+3]);
    const float* w0 = eAr + (size_t)d0*8;
    const float* w1 = eAr + (size_t)d1*8;
    const float* w2 = eAr + (size_t)d2*8;
    const float* w3 = eAr + (size_t)d3*8;
    uint2 p0 = *(const uint2*)(xbp + (size_t)d0*512 + l8);
    uint2 p1 = *(const uint2*)(xbp + (size_t)d1*512 + l8);
    uint2 p2 = *(const uint2*)(xbp + (size_t)d2*512 + l8);
    uint2 p3 = *(const uint2*)(xbp + (size_t)d3*512 + l8);
    // lane-parallel den: lane owns head l&7 (replicated x8 across wave)
    dnl += (w0[0*0+lw? lw:lw]);   // placeholder avoided below
    dnl -= w0[lw];                // neutralize (see real accum below)
    dnl += w0[lw] + w1[lw] + w2[lw] + w3[lw];
#pragma unroll
    for (int e=0;e<4;e++){
      const float* we = (e==0)?w0 : (e==1)?w1 : (e==2)?w2 : w3;
      uint2 pe = (e==0)?p0 : (e==1)?p1 : (e==2)?p2 : p3;
      float f0 = __uint_as_float(pe.x<<16);
      float f1 = __uint_as_float(pe.x&0xffff0000u);
      float f2 = __uint_as_float(pe.y<<16);
      float f3 = __uint_as_float(pe.y&0xffff0000u);
#pragma unroll
      for (int h=0;h<8;h++){
        const float w = we[h];
        acc[h][0] += w*f0; acc[h][1] += w*f1;
        acc[h][2] += w*f2; acc[h][3] += w*f3;
      }
    }
  }
  const int lt = (int)(n>>6) - tile0;
  const int r  = (int)(n&63);
  char* tb = (char*)g + (size_t)lt*262144 + r*512
           + ((((l>>1) ^ (r&7)))<<4) + ((l&1)<<3);
#pragma unroll
  for (int h=0;h<8;h++){
    uint2 d;
    d.x = (unsigned)f2bf(acc[h][0]) | ((unsigned)f2bf(acc[h][1])<<16);
    d.y = (unsigned)f2bf(acc[h][2]) | ((unsigned)f2bf(acc[h][3])<<16);
    *(uint2*)(tb + h*32768) = d;
  }
  if (l < 8) den[n*NH + l] = dnl;
}

// ---------------- per-head GEMM: out[n, h*64+o] = elu( (g_h[n] . W_h[o]) / den )
__global__ __launch_bounds__(256) void k_gemm2(const unsigned short* __restrict__ g,
                                               const unsigned short* __restrict__ Wt,
                                               const float* __restrict__ den,
                                               float* __restrict__ out,
                                               int tile0){
  __shared__ unsigned short As[16384];
  __shared__ unsigned short Bs[16384];
  __shared__ float linv[64];
  const int tid = threadIdx.x, w = tid>>6, l = tid&63;
  const int brow = tile0 + blockIdx.x;
  const int h = blockIdx.y;
  {
    const char* srcA = (const char*)g + (size_t)blockIdx.x*262144 + h*32768 + w*8192 + l*16;
    char* dstA = (char*)As + w*8192;
#pragma unroll
    for (int k=0;k<8;k++) GLOAD_LDS16(srcA + k*1024, dstA + k*1024);
    const char* srcB = (const char*)Wt + (size_t)h*32768 + w*8192 + l*16;
    char* dstB = (char*)Bs + w*8192;
#pragma unroll
    for (int k=0;k<8;k++) GLOAD_LDS16(srcB + k*1024, dstB + k*1024);
  }
  if (tid < 64){
    long gr = (long)brow*64 + tid;
    float dv = (gr < NN) ? den[gr*NH + h] : 1.f;
    linv[tid] = dv > 0.f ? 1.f/dv : 0.f;
  }
  asm volatile("s_waitcnt vmcnt(0)");
  __syncthreads();

  const int col = w*16 + (l&15);
  f32x4 acc[4] = {};
#pragma unroll
  for (int ks=0; ks<8; ks++){
    int chunkB = (ks*4 + (l>>4)) ^ (col&7);
    bf16x8 bfrag = *(const bf16x8*)((char*)Bs + col*512 + (chunkB<<4));
#pragma unroll
    for (int mt=0; mt<4; mt++){
      int ar_ = mt*16 + (l&15);
      int chunkA = (ks*4 + (l>>4)) ^ (ar_&7);
      bf16x8 afrag = *(const bf16x8*)((char*)As + ar_*512 + (chunkA<<4));
      acc[mt] = __builtin_amdgcn_mfma_f32_16x16x32_bf16(afrag, bfrag, acc[mt], 0,0,0);
    }
  }
#pragma unroll
  for (int mt=0; mt<4; mt++){
#pragma unroll
    for (int j=0;j<4;j++){
      int r = mt*16 + (l>>4)*4 + j;
      long gr = (long)brow*64 + r;
      if (gr < NN){
        float v = acc[mt][j] * linv[r];
        out[gr*NC + h*64 + col] = v>0.f ? v : expm1f(v);
      }
    }
  }
}

extern "C" void kernel_launch(void* const* d_in, const int* in_sizes, int n_in,
                              void* d_out, int out_size, void* d_ws, size_t ws_size,
                              hipStream_t stream){
  const float* x   = (const float*)d_in[0];
  const int*   src = (const int*)d_in[1];
  const int*   dst = (const int*)d_in[2];
  const float* Ws  = (const float*)d_in[3];
  const float* Av  = (const float*)d_in[4];
  const int E = in_sizes[1];
  const int NB = (E + EPB - 1) / EPB;

  char* ws = (char*)d_ws;
  size_t off = 0;
  auto alloc = [&](size_t bytes)->void*{
    void* p = ws + off; off += (bytes + 255) & ~(size_t)255; return p;
  };
  unsigned short* xb   = (unsigned short*)alloc((size_t)50048*512);
  float* eAr           = (float*)alloc((size_t)50048*NH*4);
  float* atil          = (float*)alloc(8*256*4);
  float* den           = (float*)alloc((size_t)50048*NH*4);
  unsigned short* Wt   = (unsigned short*)alloc((size_t)8*32768);
  int*   cnt           = (int*)alloc(50304*4);
  int*   row_ptr       = (int*)alloc(50304*4);
  int*   M             = (int*)alloc((size_t)NBK*256*4);
  int*   tot           = (int*)alloc(512*4);
  int*   bOff          = (int*)alloc(512*4);
  int*   bsums         = (int*)alloc(64*4);
  int*   col           = (int*)alloc(((size_t)E + 3*NN + 16)*4);
  unsigned short* g    = (unsigned short*)alloc((size_t)CHUNK_TILES*262144);
  unsigned long long* ebuf = (unsigned long long*)g;

  k_prep_w<<<8,256,0,stream>>>(Ws, Wt);
  k_atil<<<8,256,0,stream>>>(Ws, Av, atil);
  k_xbar<<<12501,256,0,stream>>>(x, atil, xb, eAr);

  k_bhist<<<NB,256,0,stream>>>(src, M, E, NB);
  k_bscan<<<NBK,256,0,stream>>>(M, tot, NB);
  k_bscan2<<<1,512,0,stream>>>(tot, bOff);
  k_bscat<<<NB,256,0,stream>>>(src, dst, M, bOff, ebuf, E, NB);
  k_bcnt<<<NBK,256,0,stream>>>(ebuf, bOff, cnt);
  k_scan1<<<49,256,0,stream>>>(cnt, row_ptr, bsums, NN+1);
  k_scan2<<<1,64,0,stream>>>(bsums, 49);
  k_scan3<<<49,256,0,stream>>>(row_ptr, bsums, NN+1);
  k_padfill<<<196,256,0,stream>>>(cnt, row_ptr, col);
  k_fscat<<<NBK,256,0,stream>>>(ebuf, bOff, row_ptr, col);

  int tile0 = 0;
  while (tile0 < NTILES){
    int tiles = NTILES - tile0 < CHUNK_TILES ? NTILES - tile0 : CHUNK_TILES;
    k_aggr2<<<tiles*16,256,0,stream>>>(row_ptr, col, xb, eAr, g, den, tile0);
    k_gemm2<<<dim3(tiles,8),256,0,stream>>>(g, Wt, den, (float*)d_out, tile0);
    tile0 += tiles;
  }
}

// Round 6
// 337.138 us; speedup vs baseline: 1.9070x; 1.1261x over previous
//
#include <hip/hip_runtime.h>
#include <hip/hip_bf16.h>

#define NN 50000
#define INF 256
#define NH 8
#define OUTF 64
#define NC 512
#define NTILES 782          // ceil(50000/64)
#define EPB 8192            // edges per sort block
#define NBK 391             // buckets: node>>7, 50000/128

typedef __attribute__((ext_vector_type(8))) short bf16x8;
typedef __attribute__((ext_vector_type(4))) float f32x4;
typedef unsigned long long u64;

__device__ __forceinline__ unsigned short f2bf(float f){
  unsigned u = __float_as_uint(f);
  u += 0x7FFFu + ((u>>16)&1u);
  return (unsigned short)(u>>16);
}

#define GLOAD_LDS16(g, s) \
  __builtin_amdgcn_global_load_lds((const __attribute__((address_space(1))) void*)(g), \
                                   (__attribute__((address_space(3))) void*)(s), 16, 0, 0)

// ---------- W -> per-head swizzled bf16 tiles (64 rows x 256 K)
__global__ __launch_bounds__(256) void k_prep_w(const float* __restrict__ W,
                                                unsigned short* __restrict__ Wt){
  const int tid = threadIdx.x;
  const int r = tid>>2, cb = (tid&3)*64;
  char* tile = (char*)(Wt + (size_t)blockIdx.x*16384);
  const float* Wr = W + ((long)blockIdx.x*64 + r)*INF;
#pragma unroll
  for (int i=0;i<16;i++){
    int c = cb + i*4;
    float4 v = *(const float4*)(Wr + c);
    ushort4 b; b.x=f2bf(v.x); b.y=f2bf(v.y); b.z=f2bf(v.z); b.w=f2bf(v.w);
    int addr = r*512 + ((((c>>3) ^ (r&7)))<<4) + ((c&7)<<1);
    *(ushort4*)(tile + addr) = b;
  }
}

// ---------- atil[h][f] = sum_o W[h*64+o][f] * a_r[h][o]
__global__ void k_atil(const float* __restrict__ W, const float* __restrict__ As,
                       float* __restrict__ atil){
  const int h = blockIdx.x, f = threadIdx.x;
  float s = 0.f;
  for (int o=0;o<64;o++) s += W[((long)h*64+o)*INF + f] * As[h*128 + 64 + o];
  atil[h*256 + f] = s;
}

// ---------- per node: xb (bf16 row) + eAr[n][h] = exp(x[n].atil[h])
__global__ __launch_bounds__(256) void k_xbar(const float* __restrict__ x,
                                              const float* __restrict__ atil,
                                              unsigned short* __restrict__ xb,
                                              float* __restrict__ eAr){
  const int tid = threadIdx.x, w = tid>>6, l = tid&63;
  const long n = (long)blockIdx.x*4 + w;
  if (n > NN) return;
  if (n == NN){   // zero sentinel row
    uint2 z; z.x=0; z.y=0;
    *(uint2*)((char*)xb + (size_t)n*512 + l*8) = z;
    if (l < 8) eAr[n*NH + l] = 0.f;
    return;
  }
  float4 v = *(const float4*)(x + n*INF + l*4);
  uint2 d;
  d.x = (unsigned)f2bf(v.x) | ((unsigned)f2bf(v.y)<<16);
  d.y = (unsigned)f2bf(v.z) | ((unsigned)f2bf(v.w)<<16);
  *(uint2*)((char*)xb + (size_t)n*512 + l*8) = d;
  float p[8];
#pragma unroll
  for (int h=0;h<8;h++){
    float4 a = *(const float4*)(atil + h*256 + l*4);
    p[h] = v.x*a.x + v.y*a.y + v.z*a.z + v.w*a.w;
  }
#pragma unroll
  for (int off=1; off<64; off<<=1){
#pragma unroll
    for (int h=0;h<8;h++) p[h] += __shfl_xor(p[h], off, 64);
  }
  if (l < 8){
    float e = p[0];
#pragma unroll
    for (int h=1;h<8;h++) if (l==h) e = p[h];
    eAr[n*NH + l] = __expf(e);
  }
}

// ---------------- CSR build: bucketed counting sort, no global atomics
__global__ __launch_bounds__(256) void k_bhist(const int* __restrict__ src,
                                               int* __restrict__ M, int E, int NB){
  __shared__ int h[NBK];
  const int tid = threadIdx.x, b = blockIdx.x;
  for (int i=tid;i<NBK;i+=256) h[i]=0;
  __syncthreads();
  const int base = b*EPB;
  const int lim = min(E-base, EPB);
  for (int i=tid;i<lim;i+=256) atomicAdd(&h[src[base+i]>>7], 1);
  __syncthreads();
  for (int i=tid;i<NBK;i+=256) M[(long)i*NB + b] = h[i];
}

// per-bucket exclusive scan over blocks (in place) + bucket totals
__global__ __launch_bounds__(256) void k_bscan(int* __restrict__ M,
                                               int* __restrict__ tot, int NB){
  __shared__ int lds[256];
  const int k = blockIdx.x, tid = threadIdx.x;
  int v = (tid<NB) ? M[(long)k*NB+tid] : 0;
  const int orig = v;
  lds[tid]=v; __syncthreads();
  for (int off=1; off<256; off<<=1){
    int a = (tid>=off)? lds[tid-off] : 0;
    __syncthreads(); lds[tid]+=a; __syncthreads();
  }
  if (tid<NB) M[(long)k*NB+tid] = lds[tid]-orig;
  if (tid==255) tot[k] = lds[255];
}

// generic small exclusive scan (n < 512), out[0..n], out[n]=total
__global__ __launch_bounds__(512) void k_sscan(const int* __restrict__ in,
                                               int* __restrict__ out, int n){
  __shared__ int lds[512];
  const int tid = threadIdx.x;
  int v = (tid<n)? in[tid] : 0;
  const int orig = v;
  lds[tid]=v; __syncthreads();
  for (int off=1; off<512; off<<=1){
    int a = (tid>=off)? lds[tid-off] : 0;
    __syncthreads(); lds[tid]+=a; __syncthreads();
  }
  if (tid<=n) out[tid] = lds[tid]-orig;
}

// bucket scatter of (src,dst) pairs via LDS cursors
__global__ __launch_bounds__(256) void k_bscat(const int* __restrict__ src,
                                               const int* __restrict__ dst,
                                               const int* __restrict__ M,
                                               const int* __restrict__ bOff,
                                               u64* __restrict__ ebuf,
                                               int E, int NB){
  __shared__ int cur[NBK];
  const int tid = threadIdx.x, b = blockIdx.x;
  for (int i=tid;i<NBK;i+=256) cur[i] = bOff[i] + M[(long)i*NB + b];
  __syncthreads();
  const int base = b*EPB;
  const int lim = min(E-base, EPB);
  for (int i=tid;i<lim;i+=256){
    int s = src[base+i], d = dst[base+i];
    int p = atomicAdd(&cur[s>>7], 1);
    ebuf[p] = ((u64)(unsigned)d<<32) | (unsigned)s;
  }
}

// per-bucket node counts + padded(8) bucket total
__global__ __launch_bounds__(256) void k_bcnt2(const u64* __restrict__ ebuf,
                                               const int* __restrict__ bOff,
                                               int* __restrict__ cnt,
                                               int* __restrict__ pbTot){
  __shared__ int h[128];
  __shared__ int ps[128];
  const int k = blockIdx.x, tid = threadIdx.x;
  if (tid<128) h[tid]=0;
  __syncthreads();
  const int beg = bOff[k], end = bOff[k+1];
  for (int i=beg+tid; i<end; i+=256)
    atomicAdd(&h[(int)(unsigned)ebuf[i] & 127], 1);
  __syncthreads();
  if (tid<128){
    cnt[(k<<7)+tid] = h[tid];
    ps[tid] = (h[tid]+7)&~7;
  }
  __syncthreads();
  for (int off=64; off>0; off>>=1){
    if (tid<off) ps[tid] += ps[tid+off];
    __syncthreads();
  }
  if (tid==0) pbTot[k] = ps[0];
}

// finalize: local padded scan -> row_ptr, scatter, padfill — all per bucket
__global__ __launch_bounds__(256) void k_final(const u64* __restrict__ ebuf,
                                               const int* __restrict__ bOff,
                                               const int* __restrict__ cnt,
                                               const int* __restrict__ pbOff,
                                               int* __restrict__ row_ptr,
                                               int* __restrict__ col){
  __shared__ int s[128];
  __shared__ int cur[128];
  __shared__ int pend[128];
  const int k = blockIdx.x, tid = threadIdx.x;
  int c = 0, pc = 0;
  if (tid<128){
    c = cnt[(k<<7)+tid];
    pc = (c+7)&~7;
    s[tid] = pc;
  }
  __syncthreads();
  for (int off=1; off<128; off<<=1){
    int a = (tid>=off && tid<128)? s[tid-off] : 0;
    __syncthreads();
    if (tid<128) s[tid] += a;
    __syncthreads();
  }
  const int base = pbOff[k];
  if (tid<128){
    int rp = base + s[tid] - pc;
    row_ptr[(k<<7)+tid] = rp;
    cur[tid] = rp;
    pend[tid] = rp + pc;
  }
  __syncthreads();
  const int beg = bOff[k], end = bOff[k+1];
  for (int i=beg+tid; i<end; i+=256){
    u64 e = ebuf[i];
    int sn = (int)(unsigned)e;
    int d  = (int)(e>>32);
    int p = atomicAdd(&cur[sn&127], 1);
    col[p] = d;
  }
  __syncthreads();
  if (tid<128){
    for (int i=cur[tid]; i<pend[tid]; i++) col[i] = NN;  // sentinel
  }
}

// ---------------- aggregation: scalar cols/weights, unroll-8
__global__ __launch_bounds__(256) void k_aggr2(const int* __restrict__ row_ptr,
                                               const int* __restrict__ col,
                                               const unsigned short* __restrict__ xb,
                                               const float* __restrict__ eAr,
                                               unsigned short* __restrict__ g,
                                               float* __restrict__ den,
                                               int tile0){
  const int tid = threadIdx.x, l = tid&63;
  const long n = (long)tile0*64 + blockIdx.x*4 + (tid>>6);
  if (n >= NN) return;
  const int beg = __builtin_amdgcn_readfirstlane(row_ptr[n]);
  const int end = __builtin_amdgcn_readfirstlane(row_ptr[n+1]);
  const char* xbp = (const char*)xb;
  float acc[8][4] = {};
  float dnl = 0.f;
  const long l8 = (long)l*8;
  const int lw = l&7;
  for (int i=beg; i<end; i+=8){
    int cc[8];
#pragma unroll
    for (int e=0;e<8;e++) cc[e] = __builtin_amdgcn_readfirstlane(col[i+e]);
    uint2 q[8];
#pragma unroll
    for (int e=0;e<8;e++) q[e] = *(const uint2*)(xbp + (size_t)cc[e]*512 + l8);
    float wl[8];
#pragma unroll
    for (int e=0;e<8;e++) wl[e] = eAr[(size_t)cc[e]*NH + lw];
#pragma unroll
    for (int e=0;e<8;e++) dnl += wl[e];
#pragma unroll
    for (int e=0;e<8;e++){
      const float* we = eAr + (size_t)cc[e]*NH;
      float f0 = __uint_as_float(q[e].x<<16);
      float f1 = __uint_as_float(q[e].x&0xffff0000u);
      float f2 = __uint_as_float(q[e].y<<16);
      float f3 = __uint_as_float(q[e].y&0xffff0000u);
#pragma unroll
      for (int h=0;h<8;h++){
        const float w = we[h];
        acc[h][0] += w*f0; acc[h][1] += w*f1;
        acc[h][2] += w*f2; acc[h][3] += w*f3;
      }
    }
  }
  const int lt = (int)(n>>6) - tile0;
  const int r  = (int)(n&63);
  char* tb = (char*)g + (size_t)lt*262144 + r*512
           + ((((l>>1) ^ (r&7)))<<4) + ((l&1)<<3);
#pragma unroll
  for (int h=0;h<8;h++){
    uint2 d;
    d.x = (unsigned)f2bf(acc[h][0]) | ((unsigned)f2bf(acc[h][1])<<16);
    d.y = (unsigned)f2bf(acc[h][2]) | ((unsigned)f2bf(acc[h][3])<<16);
    *(uint2*)(tb + h*32768) = d;
  }
  if (l < 8) den[n*NH + l] = dnl;
}

// ---------------- per-head GEMM: out[n, h*64+o] = elu( (g_h[n] . W_h[o]) / den )
__global__ __launch_bounds__(256) void k_gemm2(const unsigned short* __restrict__ g,
                                               const unsigned short* __restrict__ Wt,
                                               const float* __restrict__ den,
                                               float* __restrict__ out,
                                               int tile0){
  __shared__ unsigned short As[16384];
  __shared__ unsigned short Bs[16384];
  __shared__ float linv[64];
  const int tid = threadIdx.x, w = tid>>6, l = tid&63;
  const int brow = tile0 + blockIdx.x;
  const int h = blockIdx.y;
  {
    const char* srcA = (const char*)g + (size_t)blockIdx.x*262144 + h*32768 + w*8192 + l*16;
    char* dstA = (char*)As + w*8192;
#pragma unroll
    for (int k=0;k<8;k++) GLOAD_LDS16(srcA + k*1024, dstA + k*1024);
    const char* srcB = (const char*)Wt + (size_t)h*32768 + w*8192 + l*16;
    char* dstB = (char*)Bs + w*8192;
#pragma unroll
    for (int k=0;k<8;k++) GLOAD_LDS16(srcB + k*1024, dstB + k*1024);
  }
  if (tid < 64){
    long gr = (long)brow*64 + tid;
    float dv = (gr < NN) ? den[gr*NH + h] : 1.f;
    linv[tid] = dv > 0.f ? 1.f/dv : 0.f;
  }
  asm volatile("s_waitcnt vmcnt(0)");
  __syncthreads();

  const int col = w*16 + (l&15);
  f32x4 acc[4] = {};
#pragma unroll
  for (int ks=0; ks<8; ks++){
    int chunkB = (ks*4 + (l>>4)) ^ (col&7);
    bf16x8 bfrag = *(const bf16x8*)((char*)Bs + col*512 + (chunkB<<4));
#pragma unroll
    for (int mt=0; mt<4; mt++){
      int ar_ = mt*16 + (l&15);
      int chunkA = (ks*4 + (l>>4)) ^ (ar_&7);
      bf16x8 afrag = *(const bf16x8*)((char*)As + ar_*512 + (chunkA<<4));
      acc[mt] = __builtin_amdgcn_mfma_f32_16x16x32_bf16(afrag, bfrag, acc[mt], 0,0,0);
    }
  }
#pragma unroll
  for (int mt=0; mt<4; mt++){
#pragma unroll
    for (int j=0;j<4;j++){
      int r = mt*16 + (l>>4)*4 + j;
      long gr = (long)brow*64 + r;
      if (gr < NN){
        float v = acc[mt][j] * linv[r];
        out[gr*NC + h*64 + col] = v>0.f ? v : expm1f(v);
      }
    }
  }
}

extern "C" void kernel_launch(void* const* d_in, const int* in_sizes, int n_in,
                              void* d_out, int out_size, void* d_ws, size_t ws_size,
                              hipStream_t stream){
  const float* x   = (const float*)d_in[0];
  const int*   src = (const int*)d_in[1];
  const int*   dst = (const int*)d_in[2];
  const float* Ws  = (const float*)d_in[3];
  const float* Av  = (const float*)d_in[4];
  const int E = in_sizes[1];
  const int NB = (E + EPB - 1) / EPB;

  char* ws = (char*)d_ws;
  size_t off = 0;
  auto alloc = [&](size_t bytes)->void*{
    void* p = ws + off; off += (bytes + 255) & ~(size_t)255; return p;
  };
  unsigned short* xb   = (unsigned short*)alloc((size_t)50048*512);
  float* eAr           = (float*)alloc((size_t)50048*NH*4);
  float* atil          = (float*)alloc(8*256*4);
  float* den           = (float*)alloc((size_t)50048*NH*4);
  unsigned short* Wt   = (unsigned short*)alloc((size_t)8*32768);
  int*   cnt           = (int*)alloc(50304*4);
  int*   row_ptr       = (int*)alloc(50304*4);
  int*   M             = (int*)alloc((size_t)NBK*256*4);
  int*   tot           = (int*)alloc(512*4);
  int*   bOff          = (int*)alloc(512*4);
  int*   pbTot         = (int*)alloc(512*4);
  int*   pbOff         = (int*)alloc(512*4);
  int*   col           = (int*)alloc(((size_t)E + 8*50048 + 64)*4);

  // adaptive g: as many 64-row tiles (256KB each) as workspace allows
  size_t remain = (ws_size > off + 256) ? (ws_size - off - 256) : 0;
  int chunk = (int)(remain / 262144);
  if (chunk > NTILES) chunk = NTILES;
  if (chunk < 49) chunk = 49;            // ebuf (E*8 bytes) must fit in g alias
  unsigned short* g = (unsigned short*)alloc((size_t)chunk*262144);
  u64* ebuf = (u64*)g;                   // dead before first g write

  k_prep_w<<<8,256,0,stream>>>(Ws, Wt);
  k_atil<<<8,256,0,stream>>>(Ws, Av, atil);
  k_xbar<<<12501,256,0,stream>>>(x, atil, xb, eAr);

  k_bhist<<<NB,256,0,stream>>>(src, M, E, NB);
  k_bscan<<<NBK,256,0,stream>>>(M, tot, NB);
  k_sscan<<<1,512,0,stream>>>(tot, bOff, NBK);
  k_bscat<<<NB,256,0,stream>>>(src, dst, M, bOff, ebuf, E, NB);
  k_bcnt2<<<NBK,256,0,stream>>>(ebuf, bOff, cnt, pbTot);
  k_sscan<<<1,512,0,stream>>>(pbTot, pbOff, NBK);
  k_final<<<NBK,256,0,stream>>>(ebuf, bOff, cnt, pbOff, row_ptr, col);

  int tile0 = 0;
  while (tile0 < NTILES){
    int tiles = NTILES - tile0 < chunk ? NTILES - tile0 : chunk;
    k_aggr2<<<tiles*16,256,0,stream>>>(row_ptr, col, xb, eAr, g, den, tile0);
    k_gemm2<<<dim3(tiles,8),256,0,stream>>>(g, Wt, den, (float*)d_out, tile0);
    tile0 += tiles;
  }
}

// Round 8
// 330.017 us; speedup vs baseline: 1.9482x; 1.0216x over previous
//
#include <hip/hip_runtime.h>
#include <hip/hip_bf16.h>

#define NN 50000
#define INF 256
#define NH 8
#define OUTF 64
#define NC 512
#define NTILES 782          // ceil(50000/64)
#define EPB 8192            // edges per sort block
#define NBK 391             // buckets: node>>7, 50000/128

typedef __attribute__((ext_vector_type(8))) short bf16x8;
typedef __attribute__((ext_vector_type(4))) float f32x4;
typedef __attribute__((ext_vector_type(2))) float v2f;
typedef unsigned long long u64;

__device__ __forceinline__ unsigned short f2bf(float f){
  unsigned u = __float_as_uint(f);
  u += 0x7FFFu + ((u>>16)&1u);
  return (unsigned short)(u>>16);
}

#define GLOAD_LDS16(g, s) \
  __builtin_amdgcn_global_load_lds((const __attribute__((address_space(1))) void*)(g), \
                                   (__attribute__((address_space(3))) void*)(s), 16, 0, 0)

// ---------- W -> per-head swizzled bf16 tiles (64 rows x 256 K)
__global__ __launch_bounds__(256) void k_prep_w(const float* __restrict__ W,
                                                unsigned short* __restrict__ Wt){
  const int tid = threadIdx.x;
  const int r = tid>>2, cb = (tid&3)*64;
  char* tile = (char*)(Wt + (size_t)blockIdx.x*16384);
  const float* Wr = W + ((long)blockIdx.x*64 + r)*INF;
#pragma unroll
  for (int i=0;i<16;i++){
    int c = cb + i*4;
    float4 v = *(const float4*)(Wr + c);
    ushort4 b; b.x=f2bf(v.x); b.y=f2bf(v.y); b.z=f2bf(v.z); b.w=f2bf(v.w);
    int addr = r*512 + ((((c>>3) ^ (r&7)))<<4) + ((c&7)<<1);
    *(ushort4*)(tile + addr) = b;
  }
}

// ---------- atil[h][f] = sum_o W[h*64+o][f] * a_r[h][o]
__global__ void k_atil(const float* __restrict__ W, const float* __restrict__ As,
                       float* __restrict__ atil){
  const int h = blockIdx.x, f = threadIdx.x;
  float s = 0.f;
  for (int o=0;o<64;o++) s += W[((long)h*64+o)*INF + f] * As[h*128 + 64 + o];
  atil[h*256 + f] = s;
}

// ---------- per node: xb (bf16 row) + eAr[n][h] = exp(x[n].atil[h])
__global__ __launch_bounds__(256) void k_xbar(const float* __restrict__ x,
                                              const float* __restrict__ atil,
                                              unsigned short* __restrict__ xb,
                                              float* __restrict__ eAr){
  const int tid = threadIdx.x, w = tid>>6, l = tid&63;
  const long n = (long)blockIdx.x*4 + w;
  if (n > NN) return;
  if (n == NN){   // zero sentinel row
    uint2 z; z.x=0; z.y=0;
    *(uint2*)((char*)xb + (size_t)n*512 + l*8) = z;
    if (l < 8) eAr[n*NH + l] = 0.f;
    return;
  }
  float4 v = *(const float4*)(x + n*INF + l*4);
  uint2 d;
  d.x = (unsigned)f2bf(v.x) | ((unsigned)f2bf(v.y)<<16);
  d.y = (unsigned)f2bf(v.z) | ((unsigned)f2bf(v.w)<<16);
  *(uint2*)((char*)xb + (size_t)n*512 + l*8) = d;
  float p[8];
#pragma unroll
  for (int h=0;h<8;h++){
    float4 a = *(const float4*)(atil + h*256 + l*4);
    p[h] = v.x*a.x + v.y*a.y + v.z*a.z + v.w*a.w;
  }
#pragma unroll
  for (int off=1; off<64; off<<=1){
#pragma unroll
    for (int h=0;h<8;h++) p[h] += __shfl_xor(p[h], off, 64);
  }
  if (l < 8){
    float e = p[0];
#pragma unroll
    for (int h=1;h<8;h++) if (l==h) e = p[h];
    eAr[n*NH + l] = __expf(e);
  }
}

// ---------------- CSR build: bucketed counting sort, no global atomics
__global__ __launch_bounds__(256) void k_bhist(const int* __restrict__ src,
                                               int* __restrict__ M, int E, int NB){
  __shared__ int h[NBK];
  const int tid = threadIdx.x, b = blockIdx.x;
  for (int i=tid;i<NBK;i+=256) h[i]=0;
  __syncthreads();
  const int base = b*EPB;
  const int lim = min(E-base, EPB);
  for (int i=tid;i<lim;i+=256) atomicAdd(&h[src[base+i]>>7], 1);
  __syncthreads();
  for (int i=tid;i<NBK;i+=256) M[(long)i*NB + b] = h[i];
}

// per-bucket exclusive scan over blocks (in place) + bucket totals
__global__ __launch_bounds__(256) void k_bscan(int* __restrict__ M,
                                               int* __restrict__ tot, int NB){
  __shared__ int lds[256];
  const int k = blockIdx.x, tid = threadIdx.x;
  int v = (tid<NB) ? M[(long)k*NB+tid] : 0;
  const int orig = v;
  lds[tid]=v; __syncthreads();
  for (int off=1; off<256; off<<=1){
    int a = (tid>=off)? lds[tid-off] : 0;
    __syncthreads(); lds[tid]+=a; __syncthreads();
  }
  if (tid<NB) M[(long)k*NB+tid] = lds[tid]-orig;
  if (tid==255) tot[k] = lds[255];
}

// generic small exclusive scan (n < 512), out[0..n], out[n]=total
__global__ __launch_bounds__(512) void k_sscan(const int* __restrict__ in,
                                               int* __restrict__ out, int n){
  __shared__ int lds[512];
  const int tid = threadIdx.x;
  int v = (tid<n)? in[tid] : 0;
  const int orig = v;
  lds[tid]=v; __syncthreads();
  for (int off=1; off<512; off<<=1){
    int a = (tid>=off)? lds[tid-off] : 0;
    __syncthreads(); lds[tid]+=a; __syncthreads();
  }
  if (tid<=n) out[tid] = lds[tid]-orig;
}

// bucket scatter of (src,dst) pairs via LDS cursors
__global__ __launch_bounds__(256) void k_bscat(const int* __restrict__ src,
                                               const int* __restrict__ dst,
                                               const int* __restrict__ M,
                                               const int* __restrict__ bOff,
                                               u64* __restrict__ ebuf,
                                               int E, int NB){
  __shared__ int cur[NBK];
  const int tid = threadIdx.x, b = blockIdx.x;
  for (int i=tid;i<NBK;i+=256) cur[i] = bOff[i] + M[(long)i*NB + b];
  __syncthreads();
  const int base = b*EPB;
  const int lim = min(E-base, EPB);
  for (int i=tid;i<lim;i+=256){
    int s = src[base+i], d = dst[base+i];
    int p = atomicAdd(&cur[s>>7], 1);
    ebuf[p] = ((u64)(unsigned)d<<32) | (unsigned)s;
  }
}

// per-bucket node counts + padded(8) bucket total
__global__ __launch_bounds__(256) void k_bcnt2(const u64* __restrict__ ebuf,
                                               const int* __restrict__ bOff,
                                               int* __restrict__ cnt,
                                               int* __restrict__ pbTot){
  __shared__ int h[128];
  __shared__ int ps[128];
  const int k = blockIdx.x, tid = threadIdx.x;
  if (tid<128) h[tid]=0;
  __syncthreads();
  const int beg = bOff[k], end = bOff[k+1];
  for (int i=beg+tid; i<end; i+=256)
    atomicAdd(&h[(int)(unsigned)ebuf[i] & 127], 1);
  __syncthreads();
  if (tid<128){
    cnt[(k<<7)+tid] = h[tid];
    ps[tid] = (h[tid]+7)&~7;
  }
  __syncthreads();
  for (int off=64; off>0; off>>=1){
    if (tid<off) ps[tid] += ps[tid+off];
    __syncthreads();
  }
  if (tid==0) pbTot[k] = ps[0];
}

// finalize: local padded scan -> row_ptr, scatter, padfill — all per bucket
__global__ __launch_bounds__(256) void k_final(const u64* __restrict__ ebuf,
                                               const int* __restrict__ bOff,
                                               const int* __restrict__ cnt,
                                               const int* __restrict__ pbOff,
                                               int* __restrict__ row_ptr,
                                               int* __restrict__ col){
  __shared__ int s[128];
  __shared__ int cur[128];
  __shared__ int pend[128];
  const int k = blockIdx.x, tid = threadIdx.x;
  int c = 0, pc = 0;
  if (tid<128){
    c = cnt[(k<<7)+tid];
    pc = (c+7)&~7;
    s[tid] = pc;
  }
  __syncthreads();
  for (int off=1; off<128; off<<=1){
    int a = (tid>=off && tid<128)? s[tid-off] : 0;
    __syncthreads();
    if (tid<128) s[tid] += a;
    __syncthreads();
  }
  const int base = pbOff[k];
  if (tid<128){
    int rp = base + s[tid] - pc;
    row_ptr[(k<<7)+tid] = rp;
    cur[tid] = rp;
    pend[tid] = rp + pc;
  }
  __syncthreads();
  const int beg = bOff[k], end = bOff[k+1];
  for (int i=beg+tid; i<end; i+=256){
    u64 e = ebuf[i];
    int sn = (int)(unsigned)e;
    int d  = (int)(e>>32);
    int p = atomicAdd(&cur[sn&127], 1);
    col[p] = d;
  }
  __syncthreads();
  if (tid<128){
    for (int i=cur[tid]; i<pend[tid]; i++) col[i] = NN;  // sentinel
  }
}

// ---------------- aggregation: scalar cols/weights, unroll-8, packed f32 FMA
__global__ __launch_bounds__(256) void k_aggr2(const int* __restrict__ row_ptr,
                                               const int* __restrict__ col,
                                               const unsigned short* __restrict__ xb,
                                               const float* __restrict__ eAr,
                                               unsigned short* __restrict__ g,
                                               float* __restrict__ den,
                                               int tile0){
  const int tid = threadIdx.x, l = tid&63;
  const long n = (long)tile0*64 + blockIdx.x*4 + (tid>>6);
  if (n >= NN) return;
  const int beg = __builtin_amdgcn_readfirstlane(row_ptr[n]);
  const int end = __builtin_amdgcn_readfirstlane(row_ptr[n+1]);
  const char* xbp = (const char*)xb;
  v2f acc[8][2] = {};
  float dnl = 0.f;
  const long l8 = (long)l*8;
  const int lw = l&7;
  for (int i=beg; i<end; i+=8){
    int cc[8];
#pragma unroll
    for (int e=0;e<8;e++) cc[e] = __builtin_amdgcn_readfirstlane(col[i+e]);
    uint2 q[8];
#pragma unroll
    for (int e=0;e<8;e++) q[e] = *(const uint2*)(xbp + (size_t)cc[e]*512 + l8);
    float wl[8];
#pragma unroll
    for (int e=0;e<8;e++) wl[e] = eAr[(size_t)cc[e]*NH + lw];
#pragma unroll
    for (int e=0;e<8;e++) dnl += wl[e];
#pragma unroll
    for (int e=0;e<8;e++){
      const float* we = eAr + (size_t)cc[e]*NH;
      v2f f01, f23;
      f01.x = __uint_as_float(q[e].x<<16);
      f01.y = __uint_as_float(q[e].x&0xffff0000u);
      f23.x = __uint_as_float(q[e].y<<16);
      f23.y = __uint_as_float(q[e].y&0xffff0000u);
#pragma unroll
      for (int h=0;h<8;h++){
        const float w = we[h];
        v2f w2; w2.x = w; w2.y = w;
        acc[h][0] = __builtin_elementwise_fma(w2, f01, acc[h][0]);
        acc[h][1] = __builtin_elementwise_fma(w2, f23, acc[h][1]);
      }
    }
  }
  const int lt = (int)(n>>6) - tile0;
  const int r  = (int)(n&63);
  char* tb = (char*)g + (size_t)lt*262144 + r*512
           + ((((l>>1) ^ (r&7)))<<4) + ((l&1)<<3);
#pragma unroll
  for (int h=0;h<8;h++){
    uint2 d;
    d.x = (unsigned)f2bf(acc[h][0].x) | ((unsigned)f2bf(acc[h][0].y)<<16);
    d.y = (unsigned)f2bf(acc[h][1].x) | ((unsigned)f2bf(acc[h][1].y)<<16);
    *(uint2*)(tb + h*32768) = d;
  }
  if (l < 8) den[n*NH + l] = dnl;
}

// ---------------- per-head GEMM: out[n, h*64+o] = elu( (g_h[n] . W_h[o]) / den )
__global__ __launch_bounds__(256) void k_gemm2(const unsigned short* __restrict__ g,
                                               const unsigned short* __restrict__ Wt,
                                               const float* __restrict__ den,
                                               float* __restrict__ out,
                                               int tile0){
  __shared__ unsigned short As[16384];
  __shared__ unsigned short Bs[16384];
  __shared__ float linv[64];
  const int tid = threadIdx.x, w = tid>>6, l = tid&63;
  const int brow = tile0 + blockIdx.x;
  const int h = blockIdx.y;
  {
    const char* srcA = (const char*)g + (size_t)blockIdx.x*262144 + h*32768 + w*8192 + l*16;
    char* dstA = (char*)As + w*8192;
#pragma unroll
    for (int k=0;k<8;k++) GLOAD_LDS16(srcA + k*1024, dstA + k*1024);
    const char* srcB = (const char*)Wt + (size_t)h*32768 + w*8192 + l*16;
    char* dstB = (char*)Bs + w*8192;
#pragma unroll
    for (int k=0;k<8;k++) GLOAD_LDS16(srcB + k*1024, dstB + k*1024);
  }
  if (tid < 64){
    long gr = (long)brow*64 + tid;
    float dv = (gr < NN) ? den[gr*NH + h] : 1.f;
    linv[tid] = dv > 0.f ? 1.f/dv : 0.f;
  }
  asm volatile("s_waitcnt vmcnt(0)");
  __syncthreads();

  const int col = w*16 + (l&15);
  f32x4 acc[4] = {};
#pragma unroll
  for (int ks=0; ks<8; ks++){
    int chunkB = (ks*4 + (l>>4)) ^ (col&7);
    bf16x8 bfrag = *(const bf16x8*)((char*)Bs + col*512 + (chunkB<<4));
#pragma unroll
    for (int mt=0; mt<4; mt++){
      int ar_ = mt*16 + (l&15);
      int chunkA = (ks*4 + (l>>4)) ^ (ar_&7);
      bf16x8 afrag = *(const bf16x8*)((char*)As + ar_*512 + (chunkA<<4));
      acc[mt] = __builtin_amdgcn_mfma_f32_16x16x32_bf16(afrag, bfrag, acc[mt], 0,0,0);
    }
  }
#pragma unroll
  for (int mt=0; mt<4; mt++){
#pragma unroll
    for (int j=0;j<4;j++){
      int r = mt*16 + (l>>4)*4 + j;
      long gr = (long)brow*64 + r;
      if (gr < NN){
        float v = acc[mt][j] * linv[r];
        out[gr*NC + h*64 + col] = v>0.f ? v : expm1f(v);
      }
    }
  }
}

extern "C" void kernel_launch(void* const* d_in, const int* in_sizes, int n_in,
                              void* d_out, int out_size, void* d_ws, size_t ws_size,
                              hipStream_t stream){
  const float* x   = (const float*)d_in[0];
  const int*   src = (const int*)d_in[1];
  const int*   dst = (const int*)d_in[2];
  const float* Ws  = (const float*)d_in[3];
  const float* Av  = (const float*)d_in[4];
  const int E = in_sizes[1];
  const int NB = (E + EPB - 1) / EPB;

  char* ws = (char*)d_ws;
  size_t off = 0;
  auto alloc = [&](size_t bytes)->void*{
    void* p = ws + off; off += (bytes + 255) & ~(size_t)255; return p;
  };
  unsigned short* xb   = (unsigned short*)alloc((size_t)50048*512);
  float* eAr           = (float*)alloc((size_t)50048*NH*4);
  float* atil          = (float*)alloc(8*256*4);
  float* den           = (float*)alloc((size_t)50048*NH*4);
  unsigned short* Wt   = (unsigned short*)alloc((size_t)8*32768);
  int*   cnt           = (int*)alloc(50304*4);
  int*   row_ptr       = (int*)alloc(50304*4);
  int*   M             = (int*)alloc((size_t)NBK*256*4);
  int*   tot           = (int*)alloc(512*4);
  int*   bOff          = (int*)alloc(512*4);
  int*   pbTot         = (int*)alloc(512*4);
  int*   pbOff         = (int*)alloc(512*4);
  int*   col           = (int*)alloc(((size_t)E + 8*50048 + 64)*4);

  // adaptive g: as many 64-row tiles (256KB each) as workspace allows
  size_t remain = (ws_size > off + 256) ? (ws_size - off - 256) : 0;
  int chunk = (int)(remain / 262144);
  if (chunk > NTILES) chunk = NTILES;
  if (chunk < 49) chunk = 49;            // ebuf (E*8 bytes) must fit in g alias
  unsigned short* g = (unsigned short*)alloc((size_t)chunk*262144);
  u64* ebuf = (u64*)g;                   // dead before first g write

  k_prep_w<<<8,256,0,stream>>>(Ws, Wt);
  k_atil<<<8,256,0,stream>>>(Ws, Av, atil);
  k_xbar<<<12501,256,0,stream>>>(x, atil, xb, eAr);

  k_bhist<<<NB,256,0,stream>>>(src, M, E, NB);
  k_bscan<<<NBK,256,0,stream>>>(M, tot, NB);
  k_sscan<<<1,512,0,stream>>>(tot, bOff, NBK);
  k_bscat<<<NB,256,0,stream>>>(src, dst, M, bOff, ebuf, E, NB);
  k_bcnt2<<<NBK,256,0,stream>>>(ebuf, bOff, cnt, pbTot);
  k_sscan<<<1,512,0,stream>>>(pbTot, pbOff, NBK);
  k_final<<<NBK,256,0,stream>>>(ebuf, bOff, cnt, pbOff, row_ptr, col);

  int tile0 = 0;
  while (tile0 < NTILES){
    int tiles = NTILES - tile0 < chunk ? NTILES - tile0 : chunk;
    k_aggr2<<<tiles*16,256,0,stream>>>(row_ptr, col, xb, eAr, g, den, tile0);
    k_gemm2<<<dim3(tiles,8),256,0,stream>>>(g, Wt, den, (float*)d_out, tile0);
    tile0 += tiles;
  }
}